// Round 12
// baseline (130.787 us; speedup 1.0000x reference)
//
#include <hip/hip_runtime.h>
#include <hip/hip_fp16.h>
#include <math.h>

#define NP 1000000
#define NE (2 * NP)
#define P 4096
#define D 64
#define H 4
#define HD 16

#define NB 512      // blocks for hist/place passes
#define PBT 1024    // threads per pass block
#define SCB 128     // bins per scan_cols block

#define KC 8        // K-splits across blocks for flash

typedef short s4v __attribute__((ext_vector_type(4)));
typedef short s8v __attribute__((ext_vector_type(8)));
typedef float f4v __attribute__((ext_vector_type(4)));

__device__ __forceinline__ float softplus_f(float x) {
    return fmaxf(x, 0.0f) + log1pf(__expf(-fabsf(x)));
}
__device__ __forceinline__ unsigned short f2bf_rne(float f) {
    unsigned int b = __float_as_uint(f);
    b += 0x7fffu + ((b >> 16) & 1u);
    return (unsigned short)(b >> 16);
}

// ---------------- pass A: per-block bin histogram ----------------
__global__ void __launch_bounds__(PBT) hist_pass(const int* __restrict__ pairs,
                                                 int* __restrict__ hists) {
    __shared__ int lh[P];
    const int tid = threadIdx.x, blk = blockIdx.x;
    for (int i = tid; i < P; i += PBT) lh[i] = 0;
    __syncthreads();
    const int lo = (int)(((long long)blk * NE) / NB);
    const int hi = (int)(((long long)(blk + 1) * NE) / NB);
    for (int i = lo + tid; i < hi; i += PBT) atomicAdd(&lh[pairs[i]], 1);
    __syncthreads();
    for (int i = tid; i < P; i += PBT) hists[(size_t)blk * P + i] = lh[i];
}

// ---------------- column prefix over blocks: chunked LDS transpose-scan ----------------
__global__ void __launch_bounds__(1024) scan_cols(int* __restrict__ hists,
                                                  int* __restrict__ totals) {
    __shared__ int buf[64][SCB];              // 32 KB
    const int bo = blockIdx.x * SCB;
    const int t = threadIdx.x;
    const int col = t & (SCB - 1);
    const int row = t >> 7;                   // 0..7
    int carry = 0;                            // valid for t < SCB
    for (int c = 0; c < NB / 64; ++c) {
#pragma unroll
        for (int r8 = 0; r8 < 64; r8 += 8)
            buf[r8 + row][col] = hists[(size_t)(c * 64 + r8 + row) * P + bo + col];
        __syncthreads();
        if (t < SCB) {
            int cr = carry;
            for (int r = 0; r < 64; ++r) { int v = buf[r][t]; buf[r][t] = cr; cr += v; }
            carry = cr;
        }
        __syncthreads();
#pragma unroll
        for (int r8 = 0; r8 < 64; r8 += 8)
            hists[(size_t)(c * 64 + r8 + row) * P + bo + col] = buf[r8 + row][col];
        __syncthreads();
    }
    if (t < SCB) totals[bo + t] = carry;
}

// ---------------- exclusive scan over 4096 bins ----------------
__global__ void __launch_bounds__(1024) scan_bins(const int* __restrict__ totals,
                                                  int* __restrict__ bin_start) {
    __shared__ int sdat[1024];
    const int t = threadIdx.x;
    int a[4]; int s = 0;
#pragma unroll
    for (int k2 = 0; k2 < 4; ++k2) { a[k2] = totals[t * 4 + k2]; s += a[k2]; }
    sdat[t] = s;
    __syncthreads();
    for (int off = 1; off < 1024; off <<= 1) {
        int v = (t >= off) ? sdat[t - off] : 0;
        __syncthreads();
        sdat[t] += v;
        __syncthreads();
    }
    int run = sdat[t] - s;
#pragma unroll
    for (int k2 = 0; k2 < 4; ++k2) { bin_start[t * 4 + k2] = run; run += a[k2]; }
    if (t == 1023) bin_start[P] = run;
}

// ---------------- pass C: scatter fp16 FEATURES, 4 independent chains/thread ----------------
__global__ void __launch_bounds__(PBT) place_pass(
        const int* __restrict__ pairs, const float* __restrict__ times,
        const float* __restrict__ mom, const float* __restrict__ pos,
        const int* __restrict__ hists, const int* __restrict__ bin_start,
        uint2* __restrict__ sfeats) {
    __shared__ int lc[P];
    __shared__ int loff[P];
    const int tid = threadIdx.x, blk = blockIdx.x;
    for (int i = tid; i < P; i += PBT) {
        lc[i] = 0;
        loff[i] = bin_start[i] + hists[(size_t)blk * P + i];
    }
    __syncthreads();
    const int lo = (int)(((long long)blk * NE) / NB);
    const int hi = (int)(((long long)(blk + 1) * NE) / NB);
    int idx[4]; bool vld[4]; int bb[4]; uint2 ff[4];
#pragma unroll
    for (int j = 0; j < 4; ++j) {
        idx[j] = lo + tid + j * PBT;
        vld[j] = idx[j] < hi;
        int i2 = vld[j] ? idx[j] : lo;
        int ev = i2 >> 1;
        bb[j] = pairs[i2];
        __half2 tm = __floats2half2_rn(times[ev], mom[ev]);
        __half2 pz = __floats2half2_rn(pos[ev], 0.0f);
        ff[j].x = *(unsigned int*)&tm;
        ff[j].y = *(unsigned int*)&pz;
    }
    int rr[4];
#pragma unroll
    for (int j = 0; j < 4; ++j)
        rr[j] = vld[j] ? atomicAdd(&lc[bb[j]], 1) : 0;
#pragma unroll
    for (int j = 0; j < 4; ++j)
        if (vld[j]) sfeats[(size_t)loff[bb[j]] + rr[j]] = ff[j];
}

// ---------------- gather-reduce: 2 waves/bin, lane = 8-entry-slot x 8-dim-group ----------------
#define GBODY(fx, fy, fz)                                                      \
    {                                                                          \
        float u0 = fmaf(fx, w0a[0], fmaf(fy, w1a[0], fmaf(fz, w2a[0], ba[0]))); \
        float u1 = fmaf(fx, w0a[1], fmaf(fy, w1a[1], fmaf(fz, w2a[1], ba[1]))); \
        float u2 = fmaf(fx, w0a[2], fmaf(fy, w1a[2], fmaf(fz, w2a[2], ba[2]))); \
        float u3 = fmaf(fx, w0a[3], fmaf(fy, w1a[3], fmaf(fz, w2a[3], ba[3]))); \
        float u4 = fmaf(fx, w0b[0], fmaf(fy, w1b[0], fmaf(fz, w2b[0], bbv[0]))); \
        float u5 = fmaf(fx, w0b[1], fmaf(fy, w1b[1], fmaf(fz, w2b[1], bbv[1]))); \
        float u6 = fmaf(fx, w0b[2], fmaf(fy, w1b[2], fmaf(fz, w2b[2], bbv[2]))); \
        float u7 = fmaf(fx, w0b[3], fmaf(fy, w1b[3], fmaf(fz, w2b[3], bbv[3]))); \
        racc[0] += __builtin_amdgcn_rcpf(__builtin_amdgcn_exp2f(u0) + 1.0f);   \
        racc[1] += __builtin_amdgcn_rcpf(__builtin_amdgcn_exp2f(u1) + 1.0f);   \
        racc[2] += __builtin_amdgcn_rcpf(__builtin_amdgcn_exp2f(u2) + 1.0f);   \
        racc[3] += __builtin_amdgcn_rcpf(__builtin_amdgcn_exp2f(u3) + 1.0f);   \
        racc[4] += __builtin_amdgcn_rcpf(__builtin_amdgcn_exp2f(u4) + 1.0f);   \
        racc[5] += __builtin_amdgcn_rcpf(__builtin_amdgcn_exp2f(u5) + 1.0f);   \
        racc[6] += __builtin_amdgcn_rcpf(__builtin_amdgcn_exp2f(u6) + 1.0f);   \
        racc[7] += __builtin_amdgcn_rcpf(__builtin_amdgcn_exp2f(u7) + 1.0f);   \
    }

#define UNPACK(u, fx, fy, fz)                                                  \
    float fx, fy, fz;                                                          \
    {                                                                          \
        float2 t2 = __half22float2(*(__half2*)&(u).x);                         \
        fx = t2.x; fy = t2.y;                                                  \
        fz = __half2float(*(__half*)&(u).y);                                   \
    }

__global__ void __launch_bounds__(512) gather_kernel(
        const uint2* __restrict__ sfeats, const int* __restrict__ bin_start,
        const float* __restrict__ Wenc, const float* __restrict__ benc,
        const float* __restrict__ pemb, float* __restrict__ x) {
    __shared__ float sred[4][16][68];
    const int tid = threadIdx.x;
    const int wv = tid >> 6, ln = tid & 63;
    const int bi = wv >> 1, hw = wv & 1;
    const int es = ln & 7, dg = ln >> 3;
    const int b = blockIdx.x * 4 + bi;
    const int d0 = dg * 8;
    const float C = 2.8853900817779268f;    // 2*log2(e)
    f4v w0a = *(const f4v*)(Wenc + d0);          f4v w0b = *(const f4v*)(Wenc + d0 + 4);
    f4v w1a = *(const f4v*)(Wenc + D + d0);      f4v w1b = *(const f4v*)(Wenc + D + d0 + 4);
    f4v w2a = *(const f4v*)(Wenc + 2 * D + d0);  f4v w2b = *(const f4v*)(Wenc + 2 * D + d0 + 4);
    f4v ba  = *(const f4v*)(benc + d0);          f4v bbv = *(const f4v*)(benc + d0 + 4);
    w0a *= C; w0b *= C; w1a *= C; w1b *= C; w2a *= C; w2b *= C; ba *= C; bbv *= C;

    const int s0 = bin_start[b], s1 = bin_start[b + 1];
    const int cnt = s1 - s0;
    const int half = (cnt + 1) >> 1;
    const int lo = s0 + hw * half;
    const int hi = hw ? s1 : (s0 + half);

    float racc[8];
#pragma unroll
    for (int j = 0; j < 8; ++j) racc[j] = 0.0f;
    int ncnt = 0;
    int base = lo;
    for (; base + 16 <= hi; base += 16) {
        uint2 u0 = sfeats[base + es];
        uint2 u1 = sfeats[base + 8 + es];
        { UNPACK(u0, fx0, fy0, fz0); GBODY(fx0, fy0, fz0); }
        { UNPACK(u1, fx1, fy1, fz1); GBODY(fx1, fy1, fz1); }
        ncnt += 2;
    }
    if (base + 8 <= hi) {
        uint2 u0 = sfeats[base + es];
        { UNPACK(u0, fx0, fy0, fz0); GBODY(fx0, fy0, fz0); }
        ncnt += 1;
        base += 8;
    }
    if (base < hi) {
        const int n = hi - base;
        const bool valid = es < n;
        uint2 u0 = valid ? sfeats[base + es] : make_uint2(0u, 0u);
        float save[8];
#pragma unroll
        for (int j = 0; j < 8; ++j) save[j] = racc[j];
        { UNPACK(u0, fx0, fy0, fz0); GBODY(fx0, fy0, fz0); }
        if (!valid) {
#pragma unroll
            for (int j = 0; j < 8; ++j) racc[j] = save[j];
        } else {
            ncnt += 1;
        }
    }
    const float fn = (float)ncnt;
    float* sw = &sred[bi][hw * 8 + es][d0];
#pragma unroll
    for (int j = 0; j < 8; ++j) sw[j] = fmaf(-2.0f, racc[j], fn);
    __syncthreads();
    if (tid < 256) {
        int bin = tid >> 6, dim = tid & 63;
        float s = 0.0f;
#pragma unroll
        for (int e2 = 0; e2 < 16; ++e2) s += sred[bin][e2][dim];
        int gb = blockIdx.x * 4 + bin;
        float c2 = (float)(bin_start[gb + 1] - bin_start[gb]);
        x[gb * D + dim] = pemb[gb * D + dim] + s / fmaxf(c2, 1.0f);
    }
}

// ---------------- QKV -> bf16 Q (row frag layout), K/V (fragment-linear) ----------------
__global__ void qkv_kernel(const float* __restrict__ x,
                           const float* __restrict__ Wq, const float* __restrict__ bq,
                           const float* __restrict__ Wk, const float* __restrict__ bk,
                           const float* __restrict__ Wv, const float* __restrict__ bv,
                           unsigned short* __restrict__ Qb, unsigned short* __restrict__ Kf,
                           unsigned short* __restrict__ Vf) {
    __shared__ float xs[4][D];
    const int r0 = blockIdx.x * 4;
    const int tid = threadIdx.x;
    xs[tid >> 6][tid & 63] = x[r0 * D + tid];
    __syncthreads();
    const int row = tid >> 6, col = tid & 63;
    float aq = bq[col], ak = bk[col], av = bv[col];
    for (int d = 0; d < D; ++d) {
        float xv = xs[row][d];
        aq = fmaf(xv, Wq[d * D + col], aq);
        ak = fmaf(xv, Wk[d * D + col], ak);
        av = fmaf(xv, Wv[d * D + col], av);
    }
    const int h = col >> 4, hd = col & 15, gr = r0 + row;
    Qb[((h * P + gr) << 4) + hd] = f2bf_rne(aq * 0.3606737602222409f);  // 0.25*log2(e)
    const int kb = gr >> 5, kk = gr & 31, up = kk >> 4;
    Kf[(((size_t)h * 128 + kb) * 64 + (hd >> 2) * 16 + (kk & 15)) * 8 + up * 4 + (hd & 3)] =
        f2bf_rne(ak);
    Vf[(((size_t)h * 128 + kb) * 64 + ((kk & 15) >> 2) * 16 + hd) * 8 + up * 4 + (kk & 3)] =
        f2bf_rne(av);
}

// ---------------- MFMA flash attention: fragment-linear operands, dual acc ----------------
__global__ void __launch_bounds__(256) flash_kernel(
        const unsigned short* __restrict__ Qb, const unsigned short* __restrict__ Kf,
        const unsigned short* __restrict__ Vf,
        float* __restrict__ pl, float* __restrict__ pout) {
    const int bid = blockIdx.x;
    const int h  = bid & 3;
    const int qt = (bid >> 2) & 63;
    const int kc = bid >> 8;
    const int tid = threadIdx.x;
    const int wv = tid >> 6, lane = tid & 63;
    const int g = lane >> 4, li = lane & 15;
    const int q0 = qt * 64 + wv * 16;

    s8v qf = {0, 0, 0, 0, 0, 0, 0, 0};
    {
        s4v ql = *(const s4v*)(Qb + ((size_t)(h * P + q0 + li) << 4) + 4 * g);
        qf[0] = ql[0]; qf[1] = ql[1]; qf[2] = ql[2]; qf[3] = ql[3];
    }
    const unsigned short* Kh = Kf + (size_t)h * 128 * 512;
    const unsigned short* Vh = Vf + (size_t)h * 128 * 512;

    f4v accA = {0.f, 0.f, 0.f, 0.f};
    f4v accB = {0.f, 0.f, 0.f, 0.f};
    float lA = 0.f, lB = 0.f;
    const int kb0 = kc * (P / KC / 32);
    const int kb1 = kb0 + P / KC / 32;
#pragma unroll 4
    for (int kb = kb0; kb < kb1; kb += 2) {
        s8v kf1 = *(const s8v*)(Kh + ((size_t)kb * 64 + lane) * 8);
        s8v kf2 = *(const s8v*)(Kh + ((size_t)(kb + 1) * 64 + lane) * 8);
        s8v vf1 = *(const s8v*)(Vh + ((size_t)kb * 64 + lane) * 8);
        s8v vf2 = *(const s8v*)(Vh + ((size_t)(kb + 1) * 64 + lane) * 8);
        s8v ka1 = {kf1[0], kf1[1], kf1[2], kf1[3], 0, 0, 0, 0};
        s8v ka2 = {kf1[4], kf1[5], kf1[6], kf1[7], 0, 0, 0, 0};
        s8v ka3 = {kf2[0], kf2[1], kf2[2], kf2[3], 0, 0, 0, 0};
        s8v ka4 = {kf2[4], kf2[5], kf2[6], kf2[7], 0, 0, 0, 0};
        f4v z = {0.f, 0.f, 0.f, 0.f};
        f4v c1 = __builtin_amdgcn_mfma_f32_16x16x32_bf16(ka1, qf, z, 0, 0, 0);
        f4v c2 = __builtin_amdgcn_mfma_f32_16x16x32_bf16(ka2, qf, z, 0, 0, 0);
        f4v c3 = __builtin_amdgcn_mfma_f32_16x16x32_bf16(ka3, qf, z, 0, 0, 0);
        f4v c4 = __builtin_amdgcn_mfma_f32_16x16x32_bf16(ka4, qf, z, 0, 0, 0);
        float p0 = __builtin_amdgcn_exp2f(c1[0]), p1 = __builtin_amdgcn_exp2f(c1[1]);
        float p2 = __builtin_amdgcn_exp2f(c1[2]), p3 = __builtin_amdgcn_exp2f(c1[3]);
        float p4 = __builtin_amdgcn_exp2f(c2[0]), p5 = __builtin_amdgcn_exp2f(c2[1]);
        float p6 = __builtin_amdgcn_exp2f(c2[2]), p7 = __builtin_amdgcn_exp2f(c2[3]);
        float p8 = __builtin_amdgcn_exp2f(c3[0]), p9 = __builtin_amdgcn_exp2f(c3[1]);
        float pa = __builtin_amdgcn_exp2f(c3[2]), pb = __builtin_amdgcn_exp2f(c3[3]);
        float pc = __builtin_amdgcn_exp2f(c4[0]), pd = __builtin_amdgcn_exp2f(c4[1]);
        float pe = __builtin_amdgcn_exp2f(c4[2]), pf_ = __builtin_amdgcn_exp2f(c4[3]);
        lA += ((p0 + p1) + (p2 + p3)) + ((p4 + p5) + (p6 + p7));
        lB += ((p8 + p9) + (pa + pb)) + ((pc + pd) + (pe + pf_));
        s8v pf1, pf2;
        pf1[0] = (short)(__float_as_uint(p0) >> 16); pf1[1] = (short)(__float_as_uint(p1) >> 16);
        pf1[2] = (short)(__float_as_uint(p2) >> 16); pf1[3] = (short)(__float_as_uint(p3) >> 16);
        pf1[4] = (short)(__float_as_uint(p4) >> 16); pf1[5] = (short)(__float_as_uint(p5) >> 16);
        pf1[6] = (short)(__float_as_uint(p6) >> 16); pf1[7] = (short)(__float_as_uint(p7) >> 16);
        pf2[0] = (short)(__float_as_uint(p8) >> 16); pf2[1] = (short)(__float_as_uint(p9) >> 16);
        pf2[2] = (short)(__float_as_uint(pa) >> 16); pf2[3] = (short)(__float_as_uint(pb) >> 16);
        pf2[4] = (short)(__float_as_uint(pc) >> 16); pf2[5] = (short)(__float_as_uint(pd) >> 16);
        pf2[6] = (short)(__float_as_uint(pe) >> 16); pf2[7] = (short)(__float_as_uint(pf_) >> 16);
        accA = __builtin_amdgcn_mfma_f32_16x16x32_bf16(vf1, pf1, accA, 0, 0, 0);
        accB = __builtin_amdgcn_mfma_f32_16x16x32_bf16(vf2, pf2, accB, 0, 0, 0);
    }
    f4v acc = {accA[0] + accB[0], accA[1] + accB[1], accA[2] + accB[2], accA[3] + accB[3]};
    float l = lA + lB;
    l += __shfl_xor(l, 16, 64);
    l += __shfl_xor(l, 32, 64);
    const int q = q0 + li;
    const size_t gidx = (size_t)(h * P + q) * KC + kc;
    *(f4v*)(pout + gidx * 16 + 4 * g) = acc;
    if (lane < 16) pl[gidx] = l;
}

// ---------------- fused merge + output projection + MLP heads ----------------
__global__ void heads_kernel(const float* __restrict__ pl, const float* __restrict__ pout,
                             const float* __restrict__ Wo, const float* __restrict__ bo,
                             const float* __restrict__ Wm1, const float* __restrict__ bm1,
                             const float* __restrict__ Wm2, const float* __restrict__ bm2,
                             const float* __restrict__ Wd1, const float* __restrict__ bd1,
                             const float* __restrict__ Wd2, const float* __restrict__ bd2,
                             float* __restrict__ out) {
    __shared__ float cs[4][D];
    __shared__ float x2[4][D];
    __shared__ float hid[4][D];
    const int r0 = blockIdx.x * 4;
    const int tid = threadIdx.x;
    const int row = tid >> 6, col = tid & 63;
    // merge prologue: ctx[row][col] from K-chunk partials
    {
        const int h = col >> 4, hd = col & 15;
        const size_t gq = (size_t)(h * P + r0 + row);
        float L = 0.f, s = 0.f;
#pragma unroll
        for (int c = 0; c < KC; ++c) {
            L += pl[gq * KC + c];
            s += pout[(gq * KC + c) * 16 + hd];
        }
        cs[row][col] = s / L;
    }
    __syncthreads();
    float a = bo[col];
    for (int d = 0; d < D; ++d) a = fmaf(cs[row][d], Wo[d * D + col], a);
    x2[row][col] = a;
    __syncthreads();
    const int hc = col & 31;
    const float* W1 = (col < 32) ? Wm1 : Wd1;
    float hsum = (col < 32) ? bm1[hc] : bd1[hc];
    for (int d = 0; d < D; ++d) hsum = fmaf(x2[row][d], W1[d * 32 + hc], hsum);
    hsum = fmaxf(hsum, 0.0f);
    float w2 = (col < 32) ? Wm2[hc] : Wd2[hc];
    hid[row][col] = hsum * w2;
    __syncthreads();
    if (tid < 8) {
        int rr = tid >> 1, which = tid & 1;
        float s = which ? bd2[0] : bm2[0];
        for (int j2 = 0; j2 < 32; ++j2) s += hid[rr][which * 32 + j2];
        out[which * P + r0 + rr] = softplus_f(s);
    }
}

extern "C" void kernel_launch(void* const* d_in, const int* in_sizes, int n_in,
                              void* d_out, int out_size, void* d_ws, size_t ws_size,
                              hipStream_t stream) {
    const float* times = (const float*)d_in[0];
    const float* mom   = (const float*)d_in[1];
    const float* pos   = (const float*)d_in[2];
    const int*   pairs = (const int*)d_in[3];
    const float* Wenc  = (const float*)d_in[4];
    const float* benc  = (const float*)d_in[5];
    const float* pemb  = (const float*)d_in[6];
    const float* Wq = (const float*)d_in[7];   const float* bq = (const float*)d_in[8];
    const float* Wk = (const float*)d_in[9];   const float* bk = (const float*)d_in[10];
    const float* Wv = (const float*)d_in[11];  const float* bv = (const float*)d_in[12];
    const float* Wo = (const float*)d_in[13];  const float* bo = (const float*)d_in[14];
    const float* Wm1 = (const float*)d_in[15]; const float* bm1 = (const float*)d_in[16];
    const float* Wm2 = (const float*)d_in[17]; const float* bm2 = (const float*)d_in[18];
    const float* Wd1 = (const float*)d_in[19]; const float* bd1 = (const float*)d_in[20];
    const float* Wd2 = (const float*)d_in[21]; const float* bd2 = (const float*)d_in[22];

    char* wsb = (char*)d_ws;
    uint2* sfeats   = (uint2*)wsb;                             // NE*8 = 16 MB [reused as pout]
    int* hists      = (int*)(wsb + (size_t)NE * 8);            // NB*P = 8 MB
    int* totals     = hists + (size_t)NB * P;
    int* bin_start  = totals + P;
    float* x        = (float*)(bin_start + P + 2);             // 1 MB
    unsigned short* Qb = (unsigned short*)(x + P * D);         // 512 KB
    unsigned short* Kf = Qb + (size_t)H * P * 16;              // 512 KB
    unsigned short* Vf = Kf + (size_t)H * P * 16;              // 512 KB
    float* pl       = (float*)(Vf + (size_t)H * P * 16);       // H*P*KC
    float* pout     = (float*)wsb;                             // alias sfeats (dead after gather), 8 MB
    float* out      = (float*)d_out;

    hist_pass<<<NB, PBT, 0, stream>>>(pairs, hists);
    scan_cols<<<P / SCB, 1024, 0, stream>>>(hists, totals);
    scan_bins<<<1, 1024, 0, stream>>>(totals, bin_start);
    place_pass<<<NB, PBT, 0, stream>>>(pairs, times, mom, pos, hists, bin_start, sfeats);
    gather_kernel<<<P / 4, 512, 0, stream>>>(sfeats, bin_start, Wenc, benc, pemb, x);
    qkv_kernel<<<P / 4, 256, 0, stream>>>(x, Wq, bq, Wk, bk, Wv, bv, Qb, Kf, Vf);
    flash_kernel<<<H * (P / 64) * KC, 256, 0, stream>>>(Qb, Kf, Vf, pl, pout);
    heads_kernel<<<P / 4, 256, 0, stream>>>(pl, pout, Wo, bo, Wm1, bm1, Wm2, bm2,
                                            Wd1, bd1, Wd2, bd2, out);
}

// Round 13
// 127.659 us; speedup vs baseline: 1.0245x; 1.0245x over previous
//
#include <hip/hip_runtime.h>
#include <hip/hip_fp16.h>
#include <math.h>

#define NP 1000000
#define NE (2 * NP)
#define P 4096
#define D 64
#define H 4
#define HD 16

#define NB 512      // blocks for hist/place passes
#define PBT 1024    // threads per pass block
#define SCB 128     // bins per scan_cols block

#define KC 8        // K-splits across blocks for flash

typedef short s4v __attribute__((ext_vector_type(4)));
typedef short s8v __attribute__((ext_vector_type(8)));
typedef float f4v __attribute__((ext_vector_type(4)));

__device__ __forceinline__ float softplus_f(float x) {
    return fmaxf(x, 0.0f) + log1pf(__expf(-fabsf(x)));
}
__device__ __forceinline__ unsigned short f2bf_rne(float f) {
    unsigned int b = __float_as_uint(f);
    b += 0x7fffu + ((b >> 16) & 1u);
    return (unsigned short)(b >> 16);
}

// ---------------- pass A: per-block bin histogram ----------------
__global__ void __launch_bounds__(PBT) hist_pass(const int* __restrict__ pairs,
                                                 int* __restrict__ hists) {
    __shared__ int lh[P];
    const int tid = threadIdx.x, blk = blockIdx.x;
    for (int i = tid; i < P; i += PBT) lh[i] = 0;
    __syncthreads();
    const int lo = (int)(((long long)blk * NE) / NB);
    const int hi = (int)(((long long)(blk + 1) * NE) / NB);
    for (int i = lo + tid; i < hi; i += PBT) atomicAdd(&lh[pairs[i]], 1);
    __syncthreads();
    for (int i = tid; i < P; i += PBT) hists[(size_t)blk * P + i] = lh[i];
}

// ---------------- column prefix over blocks: chunked LDS transpose-scan ----------------
__global__ void __launch_bounds__(1024) scan_cols(int* __restrict__ hists,
                                                  int* __restrict__ totals) {
    __shared__ int buf[64][SCB];              // 32 KB
    const int bo = blockIdx.x * SCB;
    const int t = threadIdx.x;
    const int col = t & (SCB - 1);
    const int row = t >> 7;                   // 0..7
    int carry = 0;                            // valid for t < SCB
    for (int c = 0; c < NB / 64; ++c) {
#pragma unroll
        for (int r8 = 0; r8 < 64; r8 += 8)
            buf[r8 + row][col] = hists[(size_t)(c * 64 + r8 + row) * P + bo + col];
        __syncthreads();
        if (t < SCB) {
            int cr = carry;
            for (int r = 0; r < 64; ++r) { int v = buf[r][t]; buf[r][t] = cr; cr += v; }
            carry = cr;
        }
        __syncthreads();
#pragma unroll
        for (int r8 = 0; r8 < 64; r8 += 8)
            hists[(size_t)(c * 64 + r8 + row) * P + bo + col] = buf[r8 + row][col];
        __syncthreads();
    }
    if (t < SCB) totals[bo + t] = carry;
}

// ---------------- exclusive scan over 4096 bins ----------------
__global__ void __launch_bounds__(1024) scan_bins(const int* __restrict__ totals,
                                                  int* __restrict__ bin_start) {
    __shared__ int sdat[1024];
    const int t = threadIdx.x;
    int a[4]; int s = 0;
#pragma unroll
    for (int k2 = 0; k2 < 4; ++k2) { a[k2] = totals[t * 4 + k2]; s += a[k2]; }
    sdat[t] = s;
    __syncthreads();
    for (int off = 1; off < 1024; off <<= 1) {
        int v = (t >= off) ? sdat[t - off] : 0;
        __syncthreads();
        sdat[t] += v;
        __syncthreads();
    }
    int run = sdat[t] - s;
#pragma unroll
    for (int k2 = 0; k2 < 4; ++k2) { bin_start[t * 4 + k2] = run; run += a[k2]; }
    if (t == 1023) bin_start[P] = run;
}

// ---------------- pass C: scatter fp16 FEATURES, 4 independent chains/thread ----------------
__global__ void __launch_bounds__(PBT) place_pass(
        const int* __restrict__ pairs, const float* __restrict__ times,
        const float* __restrict__ mom, const float* __restrict__ pos,
        const int* __restrict__ hists, const int* __restrict__ bin_start,
        uint2* __restrict__ sfeats) {
    __shared__ int lc[P];
    __shared__ int loff[P];
    const int tid = threadIdx.x, blk = blockIdx.x;
    for (int i = tid; i < P; i += PBT) {
        lc[i] = 0;
        loff[i] = bin_start[i] + hists[(size_t)blk * P + i];
    }
    __syncthreads();
    const int lo = (int)(((long long)blk * NE) / NB);
    const int hi = (int)(((long long)(blk + 1) * NE) / NB);
    int idx[4]; bool vld[4]; int bb[4]; uint2 ff[4];
#pragma unroll
    for (int j = 0; j < 4; ++j) {
        idx[j] = lo + tid + j * PBT;
        vld[j] = idx[j] < hi;
        int i2 = vld[j] ? idx[j] : lo;
        int ev = i2 >> 1;
        bb[j] = pairs[i2];
        __half2 tm = __floats2half2_rn(times[ev], mom[ev]);
        __half2 pz = __floats2half2_rn(pos[ev], 0.0f);
        ff[j].x = *(unsigned int*)&tm;
        ff[j].y = *(unsigned int*)&pz;
    }
    int rr[4];
#pragma unroll
    for (int j = 0; j < 4; ++j)
        rr[j] = vld[j] ? atomicAdd(&lc[bb[j]], 1) : 0;
#pragma unroll
    for (int j = 0; j < 4; ++j)
        if (vld[j]) sfeats[(size_t)loff[bb[j]] + rr[j]] = ff[j];
}

// ---------------- gather-reduce: 4 waves/bin, pairwise-rcp tanh ----------------
// racc[j] accumulates 1/(exp2(u)+1); tanh-sum = ncnt - 2*racc.
// Pair trick: 1/pA + 1/pB = (pA+pB)*rcp(pA*pB) -- halves rcp count.
#define PDIM(w0_, w1_, w2_, b_, j)                                             \
    {                                                                          \
        float uA = fmaf(fAx, w0_, fmaf(fAy, w1_, fmaf(fAz, w2_, b_)));         \
        float uB = fmaf(fBx, w0_, fmaf(fBy, w1_, fmaf(fBz, w2_, b_)));         \
        float pA = __builtin_amdgcn_exp2f(uA) + 1.0f;                          \
        float pB = __builtin_amdgcn_exp2f(uB) + 1.0f;                          \
        racc[j] = fmaf(pA + pB, __builtin_amdgcn_rcpf(pA * pB), racc[j]);      \
    }
#define GBODY2()                                                               \
    PDIM(w0a[0], w1a[0], w2a[0], ba[0], 0)                                     \
    PDIM(w0a[1], w1a[1], w2a[1], ba[1], 1)                                     \
    PDIM(w0a[2], w1a[2], w2a[2], ba[2], 2)                                     \
    PDIM(w0a[3], w1a[3], w2a[3], ba[3], 3)                                     \
    PDIM(w0b[0], w1b[0], w2b[0], bbv[0], 4)                                    \
    PDIM(w0b[1], w1b[1], w2b[1], bbv[1], 5)                                    \
    PDIM(w0b[2], w1b[2], w2b[2], bbv[2], 6)                                    \
    PDIM(w0b[3], w1b[3], w2b[3], bbv[3], 7)

#define SDIM(w0_, w1_, w2_, b_, j)                                             \
    {                                                                          \
        float u = fmaf(fAx, w0_, fmaf(fAy, w1_, fmaf(fAz, w2_, b_)));          \
        racc[j] += __builtin_amdgcn_rcpf(__builtin_amdgcn_exp2f(u) + 1.0f);    \
    }
#define GBODY1()                                                               \
    SDIM(w0a[0], w1a[0], w2a[0], ba[0], 0)                                     \
    SDIM(w0a[1], w1a[1], w2a[1], ba[1], 1)                                     \
    SDIM(w0a[2], w1a[2], w2a[2], ba[2], 2)                                     \
    SDIM(w0a[3], w1a[3], w2a[3], ba[3], 3)                                     \
    SDIM(w0b[0], w1b[0], w2b[0], bbv[0], 4)                                    \
    SDIM(w0b[1], w1b[1], w2b[1], bbv[1], 5)                                    \
    SDIM(w0b[2], w1b[2], w2b[2], bbv[2], 6)                                    \
    SDIM(w0b[3], w1b[3], w2b[3], bbv[3], 7)

__global__ void __launch_bounds__(512) gather_kernel(
        const uint2* __restrict__ sfeats, const int* __restrict__ bin_start,
        const float* __restrict__ Wenc, const float* __restrict__ benc,
        const float* __restrict__ pemb, float* __restrict__ x) {
    __shared__ float sred[2][32][68];   // [bin-in-block][slot(4 quarters x 8 es)][dim+pad]
    const int tid = threadIdx.x;
    const int wv = tid >> 6, ln = tid & 63;
    const int bi = wv >> 2, qh = wv & 3;          // bin-in-block, quarter index
    const int es = ln & 7, dg = ln >> 3;
    const int b = blockIdx.x * 2 + bi;
    const int d0 = dg * 8;
    const float C = 2.8853900817779268f;    // 2*log2(e)
    f4v w0a = *(const f4v*)(Wenc + d0);          f4v w0b = *(const f4v*)(Wenc + d0 + 4);
    f4v w1a = *(const f4v*)(Wenc + D + d0);      f4v w1b = *(const f4v*)(Wenc + D + d0 + 4);
    f4v w2a = *(const f4v*)(Wenc + 2 * D + d0);  f4v w2b = *(const f4v*)(Wenc + 2 * D + d0 + 4);
    f4v ba  = *(const f4v*)(benc + d0);          f4v bbv = *(const f4v*)(benc + d0 + 4);
    w0a *= C; w0b *= C; w1a *= C; w1b *= C; w2a *= C; w2b *= C; ba *= C; bbv *= C;

    const int s0 = bin_start[b], s1 = bin_start[b + 1];
    const int cnt = s1 - s0;
    const int qs = (cnt + 3) >> 2;
    const int lo = s0 + qh * qs;
    const int hi = min(s0 + (qh + 1) * qs, s1);

    float racc[8];
#pragma unroll
    for (int j = 0; j < 8; ++j) racc[j] = 0.0f;
    int ncnt = 0;
    int base = lo;
    for (; base + 16 <= hi; base += 16) {        // 2 entries/slot: paired-rcp body
        uint2 uA = sfeats[base + es];
        uint2 uB = sfeats[base + 8 + es];
        float2 tA = __half22float2(*(__half2*)&uA.x);
        float fAx = tA.x, fAy = tA.y, fAz = __half2float(*(__half*)&uA.y);
        float2 tB = __half22float2(*(__half2*)&uB.x);
        float fBx = tB.x, fBy = tB.y, fBz = __half2float(*(__half*)&uB.y);
        GBODY2();
        ncnt += 2;
    }
    if (base + 8 <= hi) {
        uint2 uA = sfeats[base + es];
        float2 tA = __half22float2(*(__half2*)&uA.x);
        float fAx = tA.x, fAy = tA.y, fAz = __half2float(*(__half*)&uA.y);
        GBODY1();
        ncnt += 1;
        base += 8;
    }
    if (base < hi) {                              // masked tail (<8 entries)
        const int n = hi - base;
        const bool valid = es < n;
        uint2 uA = valid ? sfeats[base + es] : make_uint2(0u, 0u);
        float2 tA = __half22float2(*(__half2*)&uA.x);
        float fAx = tA.x, fAy = tA.y, fAz = __half2float(*(__half*)&uA.y);
        float save[8];
#pragma unroll
        for (int j = 0; j < 8; ++j) save[j] = racc[j];
        GBODY1();
        if (!valid) {
#pragma unroll
            for (int j = 0; j < 8; ++j) racc[j] = save[j];
        } else {
            ncnt += 1;
        }
    }
    const float fn = (float)ncnt;
    float* sw = &sred[bi][qh * 8 + es][d0];
#pragma unroll
    for (int j = 0; j < 8; ++j) sw[j] = fmaf(-2.0f, racc[j], fn);
    __syncthreads();
    if (tid < 128) {
        int bin = tid >> 6, dim = tid & 63;
        float s = 0.0f;
#pragma unroll
        for (int e2 = 0; e2 < 32; ++e2) s += sred[bin][e2][dim];
        int gb = blockIdx.x * 2 + bin;
        float c2 = (float)(bin_start[gb + 1] - bin_start[gb]);
        x[gb * D + dim] = pemb[gb * D + dim] + s / fmaxf(c2, 1.0f);
    }
}

// ---------------- QKV -> bf16 Q (row frag layout), K/V (fragment-linear) ----------------
__global__ void qkv_kernel(const float* __restrict__ x,
                           const float* __restrict__ Wq, const float* __restrict__ bq,
                           const float* __restrict__ Wk, const float* __restrict__ bk,
                           const float* __restrict__ Wv, const float* __restrict__ bv,
                           unsigned short* __restrict__ Qb, unsigned short* __restrict__ Kf,
                           unsigned short* __restrict__ Vf) {
    __shared__ float xs[4][D];
    const int r0 = blockIdx.x * 4;
    const int tid = threadIdx.x;
    xs[tid >> 6][tid & 63] = x[r0 * D + tid];
    __syncthreads();
    const int row = tid >> 6, col = tid & 63;
    float aq = bq[col], ak = bk[col], av = bv[col];
    for (int d = 0; d < D; ++d) {
        float xv = xs[row][d];
        aq = fmaf(xv, Wq[d * D + col], aq);
        ak = fmaf(xv, Wk[d * D + col], ak);
        av = fmaf(xv, Wv[d * D + col], av);
    }
    const int h = col >> 4, hd = col & 15, gr = r0 + row;
    Qb[((h * P + gr) << 4) + hd] = f2bf_rne(aq * 0.3606737602222409f);  // 0.25*log2(e)
    const int kb = gr >> 5, kk = gr & 31, up = kk >> 4;
    Kf[(((size_t)h * 128 + kb) * 64 + (hd >> 2) * 16 + (kk & 15)) * 8 + up * 4 + (hd & 3)] =
        f2bf_rne(ak);
    Vf[(((size_t)h * 128 + kb) * 64 + ((kk & 15) >> 2) * 16 + hd) * 8 + up * 4 + (kk & 3)] =
        f2bf_rne(av);
}

// ---------------- MFMA flash attention: fragment-linear operands, dual acc ----------------
__global__ void __launch_bounds__(256) flash_kernel(
        const unsigned short* __restrict__ Qb, const unsigned short* __restrict__ Kf,
        const unsigned short* __restrict__ Vf,
        float* __restrict__ pl, float* __restrict__ pout) {
    const int bid = blockIdx.x;
    const int h  = bid & 3;
    const int qt = (bid >> 2) & 63;
    const int kc = bid >> 8;
    const int tid = threadIdx.x;
    const int wv = tid >> 6, lane = tid & 63;
    const int g = lane >> 4, li = lane & 15;
    const int q0 = qt * 64 + wv * 16;

    s8v qf = {0, 0, 0, 0, 0, 0, 0, 0};
    {
        s4v ql = *(const s4v*)(Qb + ((size_t)(h * P + q0 + li) << 4) + 4 * g);
        qf[0] = ql[0]; qf[1] = ql[1]; qf[2] = ql[2]; qf[3] = ql[3];
    }
    const unsigned short* Kh = Kf + (size_t)h * 128 * 512;
    const unsigned short* Vh = Vf + (size_t)h * 128 * 512;

    f4v accA = {0.f, 0.f, 0.f, 0.f};
    f4v accB = {0.f, 0.f, 0.f, 0.f};
    float lA = 0.f, lB = 0.f;
    const int kb0 = kc * (P / KC / 32);
    const int kb1 = kb0 + P / KC / 32;
#pragma unroll 4
    for (int kb = kb0; kb < kb1; kb += 2) {
        s8v kf1 = *(const s8v*)(Kh + ((size_t)kb * 64 + lane) * 8);
        s8v kf2 = *(const s8v*)(Kh + ((size_t)(kb + 1) * 64 + lane) * 8);
        s8v vf1 = *(const s8v*)(Vh + ((size_t)kb * 64 + lane) * 8);
        s8v vf2 = *(const s8v*)(Vh + ((size_t)(kb + 1) * 64 + lane) * 8);
        s8v ka1 = {kf1[0], kf1[1], kf1[2], kf1[3], 0, 0, 0, 0};
        s8v ka2 = {kf1[4], kf1[5], kf1[6], kf1[7], 0, 0, 0, 0};
        s8v ka3 = {kf2[0], kf2[1], kf2[2], kf2[3], 0, 0, 0, 0};
        s8v ka4 = {kf2[4], kf2[5], kf2[6], kf2[7], 0, 0, 0, 0};
        f4v z = {0.f, 0.f, 0.f, 0.f};
        f4v c1 = __builtin_amdgcn_mfma_f32_16x16x32_bf16(ka1, qf, z, 0, 0, 0);
        f4v c2 = __builtin_amdgcn_mfma_f32_16x16x32_bf16(ka2, qf, z, 0, 0, 0);
        f4v c3 = __builtin_amdgcn_mfma_f32_16x16x32_bf16(ka3, qf, z, 0, 0, 0);
        f4v c4 = __builtin_amdgcn_mfma_f32_16x16x32_bf16(ka4, qf, z, 0, 0, 0);
        float p0 = __builtin_amdgcn_exp2f(c1[0]), p1 = __builtin_amdgcn_exp2f(c1[1]);
        float p2 = __builtin_amdgcn_exp2f(c1[2]), p3 = __builtin_amdgcn_exp2f(c1[3]);
        float p4 = __builtin_amdgcn_exp2f(c2[0]), p5 = __builtin_amdgcn_exp2f(c2[1]);
        float p6 = __builtin_amdgcn_exp2f(c2[2]), p7 = __builtin_amdgcn_exp2f(c2[3]);
        float p8 = __builtin_amdgcn_exp2f(c3[0]), p9 = __builtin_amdgcn_exp2f(c3[1]);
        float pa = __builtin_amdgcn_exp2f(c3[2]), pb = __builtin_amdgcn_exp2f(c3[3]);
        float pc = __builtin_amdgcn_exp2f(c4[0]), pd = __builtin_amdgcn_exp2f(c4[1]);
        float pe = __builtin_amdgcn_exp2f(c4[2]), pf_ = __builtin_amdgcn_exp2f(c4[3]);
        lA += ((p0 + p1) + (p2 + p3)) + ((p4 + p5) + (p6 + p7));
        lB += ((p8 + p9) + (pa + pb)) + ((pc + pd) + (pe + pf_));
        s8v pf1, pf2;
        pf1[0] = (short)(__float_as_uint(p0) >> 16); pf1[1] = (short)(__float_as_uint(p1) >> 16);
        pf1[2] = (short)(__float_as_uint(p2) >> 16); pf1[3] = (short)(__float_as_uint(p3) >> 16);
        pf1[4] = (short)(__float_as_uint(p4) >> 16); pf1[5] = (short)(__float_as_uint(p5) >> 16);
        pf1[6] = (short)(__float_as_uint(p6) >> 16); pf1[7] = (short)(__float_as_uint(p7) >> 16);
        pf2[0] = (short)(__float_as_uint(p8) >> 16); pf2[1] = (short)(__float_as_uint(p9) >> 16);
        pf2[2] = (short)(__float_as_uint(pa) >> 16); pf2[3] = (short)(__float_as_uint(pb) >> 16);
        pf2[4] = (short)(__float_as_uint(pc) >> 16); pf2[5] = (short)(__float_as_uint(pd) >> 16);
        pf2[6] = (short)(__float_as_uint(pe) >> 16); pf2[7] = (short)(__float_as_uint(pf_) >> 16);
        accA = __builtin_amdgcn_mfma_f32_16x16x32_bf16(vf1, pf1, accA, 0, 0, 0);
        accB = __builtin_amdgcn_mfma_f32_16x16x32_bf16(vf2, pf2, accB, 0, 0, 0);
    }
    f4v acc = {accA[0] + accB[0], accA[1] + accB[1], accA[2] + accB[2], accA[3] + accB[3]};
    float l = lA + lB;
    l += __shfl_xor(l, 16, 64);
    l += __shfl_xor(l, 32, 64);
    const int q = q0 + li;
    const size_t gidx = (size_t)(h * P + q) * KC + kc;
    *(f4v*)(pout + gidx * 16 + 4 * g) = acc;
    if (lane < 16) pl[gidx] = l;
}

// ---------------- fused merge + output projection + MLP heads ----------------
__global__ void heads_kernel(const float* __restrict__ pl, const float* __restrict__ pout,
                             const float* __restrict__ Wo, const float* __restrict__ bo,
                             const float* __restrict__ Wm1, const float* __restrict__ bm1,
                             const float* __restrict__ Wm2, const float* __restrict__ bm2,
                             const float* __restrict__ Wd1, const float* __restrict__ bd1,
                             const float* __restrict__ Wd2, const float* __restrict__ bd2,
                             float* __restrict__ out) {
    __shared__ float cs[4][D];
    __shared__ float x2[4][D];
    __shared__ float hid[4][D];
    const int r0 = blockIdx.x * 4;
    const int tid = threadIdx.x;
    const int row = tid >> 6, col = tid & 63;
    {
        const int h = col >> 4, hd = col & 15;
        const size_t gq = (size_t)(h * P + r0 + row);
        float L = 0.f, s = 0.f;
#pragma unroll
        for (int c = 0; c < KC; ++c) {
            L += pl[gq * KC + c];
            s += pout[(gq * KC + c) * 16 + hd];
        }
        cs[row][col] = s / L;
    }
    __syncthreads();
    float a = bo[col];
    for (int d = 0; d < D; ++d) a = fmaf(cs[row][d], Wo[d * D + col], a);
    x2[row][col] = a;
    __syncthreads();
    const int hc = col & 31;
    const float* W1 = (col < 32) ? Wm1 : Wd1;
    float hsum = (col < 32) ? bm1[hc] : bd1[hc];
    for (int d = 0; d < D; ++d) hsum = fmaf(x2[row][d], W1[d * 32 + hc], hsum);
    hsum = fmaxf(hsum, 0.0f);
    float w2 = (col < 32) ? Wm2[hc] : Wd2[hc];
    hid[row][col] = hsum * w2;
    __syncthreads();
    if (tid < 8) {
        int rr = tid >> 1, which = tid & 1;
        float s = which ? bd2[0] : bm2[0];
        for (int j2 = 0; j2 < 32; ++j2) s += hid[rr][which * 32 + j2];
        out[which * P + r0 + rr] = softplus_f(s);
    }
}

extern "C" void kernel_launch(void* const* d_in, const int* in_sizes, int n_in,
                              void* d_out, int out_size, void* d_ws, size_t ws_size,
                              hipStream_t stream) {
    const float* times = (const float*)d_in[0];
    const float* mom   = (const float*)d_in[1];
    const float* pos   = (const float*)d_in[2];
    const int*   pairs = (const int*)d_in[3];
    const float* Wenc  = (const float*)d_in[4];
    const float* benc  = (const float*)d_in[5];
    const float* pemb  = (const float*)d_in[6];
    const float* Wq = (const float*)d_in[7];   const float* bq = (const float*)d_in[8];
    const float* Wk = (const float*)d_in[9];   const float* bk = (const float*)d_in[10];
    const float* Wv = (const float*)d_in[11];  const float* bv = (const float*)d_in[12];
    const float* Wo = (const float*)d_in[13];  const float* bo = (const float*)d_in[14];
    const float* Wm1 = (const float*)d_in[15]; const float* bm1 = (const float*)d_in[16];
    const float* Wm2 = (const float*)d_in[17]; const float* bm2 = (const float*)d_in[18];
    const float* Wd1 = (const float*)d_in[19]; const float* bd1 = (const float*)d_in[20];
    const float* Wd2 = (const float*)d_in[21]; const float* bd2 = (const float*)d_in[22];

    char* wsb = (char*)d_ws;
    uint2* sfeats   = (uint2*)wsb;                             // NE*8 = 16 MB [reused as pout]
    int* hists      = (int*)(wsb + (size_t)NE * 8);            // NB*P = 8 MB
    int* totals     = hists + (size_t)NB * P;
    int* bin_start  = totals + P;
    float* x        = (float*)(bin_start + P + 2);             // 1 MB
    unsigned short* Qb = (unsigned short*)(x + P * D);         // 512 KB
    unsigned short* Kf = Qb + (size_t)H * P * 16;              // 512 KB
    unsigned short* Vf = Kf + (size_t)H * P * 16;              // 512 KB
    float* pl       = (float*)(Vf + (size_t)H * P * 16);       // H*P*KC
    float* pout     = (float*)wsb;                             // alias sfeats (dead after gather)
    float* out      = (float*)d_out;

    hist_pass<<<NB, PBT, 0, stream>>>(pairs, hists);
    scan_cols<<<P / SCB, 1024, 0, stream>>>(hists, totals);
    scan_bins<<<1, 1024, 0, stream>>>(totals, bin_start);
    place_pass<<<NB, PBT, 0, stream>>>(pairs, times, mom, pos, hists, bin_start, sfeats);
    gather_kernel<<<P / 2, 512, 0, stream>>>(sfeats, bin_start, Wenc, benc, pemb, x);
    qkv_kernel<<<P / 4, 256, 0, stream>>>(x, Wq, bq, Wk, bk, Wv, bv, Qb, Kf, Vf);
    flash_kernel<<<H * (P / 64) * KC, 256, 0, stream>>>(Qb, Kf, Vf, pl, pout);
    heads_kernel<<<P / 4, 256, 0, stream>>>(pl, pout, Wo, bo, Wm1, bm1, Wm2, bm2,
                                            Wd1, bd1, Wd2, bd2, out);
}

// Round 14
// 123.474 us; speedup vs baseline: 1.0592x; 1.0339x over previous
//
#include <hip/hip_runtime.h>
#include <hip/hip_fp16.h>
#include <math.h>

#define NP 1000000
#define NE (2 * NP)
#define P 4096
#define D 64
#define H 4
#define HD 16

#define NB 512      // blocks for hist/place passes
#define PBT 1024    // threads per pass block
#define SCB 128     // bins per scan_cols block

#define KC 8        // K-splits across blocks for flash

typedef short s4v __attribute__((ext_vector_type(4)));
typedef short s8v __attribute__((ext_vector_type(8)));
typedef float f4v __attribute__((ext_vector_type(4)));

__device__ __forceinline__ float softplus_f(float x) {
    return fmaxf(x, 0.0f) + log1pf(__expf(-fabsf(x)));
}
__device__ __forceinline__ unsigned short f2bf_rne(float f) {
    unsigned int b = __float_as_uint(f);
    b += 0x7fffu + ((b >> 16) & 1u);
    return (unsigned short)(b >> 16);
}

// ---------------- pass A: per-block bin histogram ----------------
__global__ void __launch_bounds__(PBT) hist_pass(const int* __restrict__ pairs,
                                                 int* __restrict__ hists) {
    __shared__ int lh[P];
    const int tid = threadIdx.x, blk = blockIdx.x;
    for (int i = tid; i < P; i += PBT) lh[i] = 0;
    __syncthreads();
    const int lo = (int)(((long long)blk * NE) / NB);
    const int hi = (int)(((long long)(blk + 1) * NE) / NB);
    for (int i = lo + tid; i < hi; i += PBT) atomicAdd(&lh[pairs[i]], 1);
    __syncthreads();
    for (int i = tid; i < P; i += PBT) hists[(size_t)blk * P + i] = lh[i];
}

// ---------------- column prefix over blocks: chunked LDS transpose-scan ----------------
__global__ void __launch_bounds__(1024) scan_cols(int* __restrict__ hists,
                                                  int* __restrict__ totals) {
    __shared__ int buf[64][SCB];              // 32 KB
    const int bo = blockIdx.x * SCB;
    const int t = threadIdx.x;
    const int col = t & (SCB - 1);
    const int row = t >> 7;                   // 0..7
    int carry = 0;                            // valid for t < SCB
    for (int c = 0; c < NB / 64; ++c) {
#pragma unroll
        for (int r8 = 0; r8 < 64; r8 += 8)
            buf[r8 + row][col] = hists[(size_t)(c * 64 + r8 + row) * P + bo + col];
        __syncthreads();
        if (t < SCB) {
            int cr = carry;
            for (int r = 0; r < 64; ++r) { int v = buf[r][t]; buf[r][t] = cr; cr += v; }
            carry = cr;
        }
        __syncthreads();
#pragma unroll
        for (int r8 = 0; r8 < 64; r8 += 8)
            hists[(size_t)(c * 64 + r8 + row) * P + bo + col] = buf[r8 + row][col];
        __syncthreads();
    }
    if (t < SCB) totals[bo + t] = carry;
}

// ---- pass C: fused {bin scan + scatter fp16 features}; block 0 publishes bin_start ----
__global__ void __launch_bounds__(PBT) place_pass(
        const int* __restrict__ pairs, const float* __restrict__ times,
        const float* __restrict__ mom, const float* __restrict__ pos,
        const int* __restrict__ hists, const int* __restrict__ totals,
        int* __restrict__ bin_start, uint2* __restrict__ sfeats) {
    __shared__ int lc[P];
    __shared__ int loff[P];
    __shared__ int sdat[1024];
    const int tid = threadIdx.x, blk = blockIdx.x;
    // exclusive scan of totals (redundant per block; ~0.4us, pipelined)
    int a[4]; int s = 0;
#pragma unroll
    for (int k2 = 0; k2 < 4; ++k2) { a[k2] = totals[tid * 4 + k2]; s += a[k2]; }
    sdat[tid] = s;
    __syncthreads();
    for (int off = 1; off < 1024; off <<= 1) {
        int v = (tid >= off) ? sdat[tid - off] : 0;
        __syncthreads();
        sdat[tid] += v;
        __syncthreads();
    }
    int run = sdat[tid] - s;
#pragma unroll
    for (int k2 = 0; k2 < 4; ++k2) {
        int i = tid * 4 + k2;
        loff[i] = run + hists[(size_t)blk * P + i];
        lc[i] = 0;
        if (blk == 0) bin_start[i] = run;
        run += a[k2];
    }
    if (blk == 0 && tid == 1023) bin_start[P] = run;
    __syncthreads();
    const int lo = (int)(((long long)blk * NE) / NB);
    const int hi = (int)(((long long)(blk + 1) * NE) / NB);
    int idx[4]; bool vld[4]; int bb[4]; uint2 ff[4];
#pragma unroll
    for (int j = 0; j < 4; ++j) {
        idx[j] = lo + tid + j * PBT;
        vld[j] = idx[j] < hi;
        int i2 = vld[j] ? idx[j] : lo;
        int ev = i2 >> 1;
        bb[j] = pairs[i2];
        __half2 tm = __floats2half2_rn(times[ev], mom[ev]);
        __half2 pz = __floats2half2_rn(pos[ev], 0.0f);
        ff[j].x = *(unsigned int*)&tm;
        ff[j].y = *(unsigned int*)&pz;
    }
    int rr[4];
#pragma unroll
    for (int j = 0; j < 4; ++j)
        rr[j] = vld[j] ? atomicAdd(&lc[bb[j]], 1) : 0;
#pragma unroll
    for (int j = 0; j < 4; ++j)
        if (vld[j]) sfeats[(size_t)loff[bb[j]] + rr[j]] = ff[j];
}

// ---------------- gather-reduce (4 waves/bin, pairwise-rcp) + fused QKV ----------------
#define PDIM(w0_, w1_, w2_, b_, j)                                             \
    {                                                                          \
        float uA = fmaf(fAx, w0_, fmaf(fAy, w1_, fmaf(fAz, w2_, b_)));         \
        float uB = fmaf(fBx, w0_, fmaf(fBy, w1_, fmaf(fBz, w2_, b_)));         \
        float pA = __builtin_amdgcn_exp2f(uA) + 1.0f;                          \
        float pB = __builtin_amdgcn_exp2f(uB) + 1.0f;                          \
        racc[j] = fmaf(pA + pB, __builtin_amdgcn_rcpf(pA * pB), racc[j]);      \
    }
#define GBODY2()                                                               \
    PDIM(w0a[0], w1a[0], w2a[0], ba[0], 0)                                     \
    PDIM(w0a[1], w1a[1], w2a[1], ba[1], 1)                                     \
    PDIM(w0a[2], w1a[2], w2a[2], ba[2], 2)                                     \
    PDIM(w0a[3], w1a[3], w2a[3], ba[3], 3)                                     \
    PDIM(w0b[0], w1b[0], w2b[0], bbv[0], 4)                                    \
    PDIM(w0b[1], w1b[1], w2b[1], bbv[1], 5)                                    \
    PDIM(w0b[2], w1b[2], w2b[2], bbv[2], 6)                                    \
    PDIM(w0b[3], w1b[3], w2b[3], bbv[3], 7)

#define SDIM(w0_, w1_, w2_, b_, j)                                             \
    {                                                                          \
        float u = fmaf(fAx, w0_, fmaf(fAy, w1_, fmaf(fAz, w2_, b_)));          \
        racc[j] += __builtin_amdgcn_rcpf(__builtin_amdgcn_exp2f(u) + 1.0f);    \
    }
#define GBODY1()                                                               \
    SDIM(w0a[0], w1a[0], w2a[0], ba[0], 0)                                     \
    SDIM(w0a[1], w1a[1], w2a[1], ba[1], 1)                                     \
    SDIM(w0a[2], w1a[2], w2a[2], ba[2], 2)                                     \
    SDIM(w0a[3], w1a[3], w2a[3], ba[3], 3)                                     \
    SDIM(w0b[0], w1b[0], w2b[0], bbv[0], 4)                                    \
    SDIM(w0b[1], w1b[1], w2b[1], bbv[1], 5)                                    \
    SDIM(w0b[2], w1b[2], w2b[2], bbv[2], 6)                                    \
    SDIM(w0b[3], w1b[3], w2b[3], bbv[3], 7)

__global__ void __launch_bounds__(512) gather_kernel(
        const uint2* __restrict__ sfeats, const int* __restrict__ bin_start,
        const float* __restrict__ Wenc, const float* __restrict__ benc,
        const float* __restrict__ pemb,
        const float* __restrict__ Wq, const float* __restrict__ bq,
        const float* __restrict__ Wk, const float* __restrict__ bk,
        const float* __restrict__ Wv, const float* __restrict__ bv,
        unsigned short* __restrict__ Qb, unsigned short* __restrict__ Kf,
        unsigned short* __restrict__ Vf) {
    __shared__ float sred[2][32][68];   // [bin-in-block][slot(4 quarters x 8 es)][dim+pad]
    __shared__ float xr[2][64];
    const int tid = threadIdx.x;
    const int wv = tid >> 6, ln = tid & 63;
    const int bi = wv >> 2, qh = wv & 3;          // bin-in-block, quarter index
    const int es = ln & 7, dg = ln >> 3;
    const int b = blockIdx.x * 2 + bi;
    const int d0 = dg * 8;
    const float C = 2.8853900817779268f;    // 2*log2(e)
    f4v w0a = *(const f4v*)(Wenc + d0);          f4v w0b = *(const f4v*)(Wenc + d0 + 4);
    f4v w1a = *(const f4v*)(Wenc + D + d0);      f4v w1b = *(const f4v*)(Wenc + D + d0 + 4);
    f4v w2a = *(const f4v*)(Wenc + 2 * D + d0);  f4v w2b = *(const f4v*)(Wenc + 2 * D + d0 + 4);
    f4v ba  = *(const f4v*)(benc + d0);          f4v bbv = *(const f4v*)(benc + d0 + 4);
    w0a *= C; w0b *= C; w1a *= C; w1b *= C; w2a *= C; w2b *= C; ba *= C; bbv *= C;

    const int s0 = bin_start[b], s1 = bin_start[b + 1];
    const int cnt = s1 - s0;
    const int qs = (cnt + 3) >> 2;
    const int lo = s0 + qh * qs;
    const int hi = min(s0 + (qh + 1) * qs, s1);

    float racc[8];
#pragma unroll
    for (int j = 0; j < 8; ++j) racc[j] = 0.0f;
    int ncnt = 0;
    int base = lo;
    for (; base + 16 <= hi; base += 16) {
        uint2 uA = sfeats[base + es];
        uint2 uB = sfeats[base + 8 + es];
        float2 tA = __half22float2(*(__half2*)&uA.x);
        float fAx = tA.x, fAy = tA.y, fAz = __half2float(*(__half*)&uA.y);
        float2 tB = __half22float2(*(__half2*)&uB.x);
        float fBx = tB.x, fBy = tB.y, fBz = __half2float(*(__half*)&uB.y);
        GBODY2();
        ncnt += 2;
    }
    if (base + 8 <= hi) {
        uint2 uA = sfeats[base + es];
        float2 tA = __half22float2(*(__half2*)&uA.x);
        float fAx = tA.x, fAy = tA.y, fAz = __half2float(*(__half*)&uA.y);
        GBODY1();
        ncnt += 1;
        base += 8;
    }
    if (base < hi) {
        const int n = hi - base;
        const bool valid = es < n;
        uint2 uA = valid ? sfeats[base + es] : make_uint2(0u, 0u);
        float2 tA = __half22float2(*(__half2*)&uA.x);
        float fAx = tA.x, fAy = tA.y, fAz = __half2float(*(__half*)&uA.y);
        float save[8];
#pragma unroll
        for (int j = 0; j < 8; ++j) save[j] = racc[j];
        GBODY1();
        if (!valid) {
#pragma unroll
            for (int j = 0; j < 8; ++j) racc[j] = save[j];
        } else {
            ncnt += 1;
        }
    }
    const float fn = (float)ncnt;
    float* sw = &sred[bi][qh * 8 + es][d0];
#pragma unroll
    for (int j = 0; j < 8; ++j) sw[j] = fmaf(-2.0f, racc[j], fn);
    __syncthreads();
    if (tid < 128) {
        int bin = tid >> 6, dim = tid & 63;
        float s = 0.0f;
#pragma unroll
        for (int e2 = 0; e2 < 32; ++e2) s += sred[bin][e2][dim];
        int gb = blockIdx.x * 2 + bin;
        float c2 = (float)(bin_start[gb + 1] - bin_start[gb]);
        xr[bin][dim] = pemb[gb * D + dim] + s / fmaxf(c2, 1.0f);
    }
    __syncthreads();
    // fused QKV: 2 rows x 192 outputs; each 64-thread wave group is uniform in `which`
    if (tid < 384) {
        const int row = (tid >= 192) ? 1 : 0;
        const int o = tid - row * 192;
        const int which = o >> 6, col = o & 63;
        const float* W = (which == 0) ? Wq : ((which == 1) ? Wk : Wv);
        const float* bia = (which == 0) ? bq : ((which == 1) ? bk : bv);
        float a = bia[col];
#pragma unroll
        for (int d = 0; d < D; ++d) a = fmaf(xr[row][d], W[d * D + col], a);
        const int gr = blockIdx.x * 2 + row;
        const int h = col >> 4, hd = col & 15;
        if (which == 0) {
            Qb[((h * P + gr) << 4) + hd] = f2bf_rne(a * 0.3606737602222409f);  // 0.25*log2(e)
        } else {
            const int kb = gr >> 5, kk = gr & 31, up = kk >> 4;
            if (which == 1)
                Kf[(((size_t)h * 128 + kb) * 64 + (hd >> 2) * 16 + (kk & 15)) * 8 +
                   up * 4 + (hd & 3)] = f2bf_rne(a);
            else
                Vf[(((size_t)h * 128 + kb) * 64 + ((kk & 15) >> 2) * 16 + hd) * 8 +
                   up * 4 + (kk & 3)] = f2bf_rne(a);
        }
    }
}

// ---------------- MFMA flash attention: fragment-linear operands, dual acc ----------------
__global__ void __launch_bounds__(256) flash_kernel(
        const unsigned short* __restrict__ Qb, const unsigned short* __restrict__ Kf,
        const unsigned short* __restrict__ Vf,
        float* __restrict__ pl, float* __restrict__ pout) {
    const int bid = blockIdx.x;
    const int h  = bid & 3;
    const int qt = (bid >> 2) & 63;
    const int kc = bid >> 8;
    const int tid = threadIdx.x;
    const int wv = tid >> 6, lane = tid & 63;
    const int g = lane >> 4, li = lane & 15;
    const int q0 = qt * 64 + wv * 16;

    s8v qf = {0, 0, 0, 0, 0, 0, 0, 0};
    {
        s4v ql = *(const s4v*)(Qb + ((size_t)(h * P + q0 + li) << 4) + 4 * g);
        qf[0] = ql[0]; qf[1] = ql[1]; qf[2] = ql[2]; qf[3] = ql[3];
    }
    const unsigned short* Kh = Kf + (size_t)h * 128 * 512;
    const unsigned short* Vh = Vf + (size_t)h * 128 * 512;

    f4v accA = {0.f, 0.f, 0.f, 0.f};
    f4v accB = {0.f, 0.f, 0.f, 0.f};
    float lA = 0.f, lB = 0.f;
    const int kb0 = kc * (P / KC / 32);
    const int kb1 = kb0 + P / KC / 32;
#pragma unroll 4
    for (int kb = kb0; kb < kb1; kb += 2) {
        s8v kf1 = *(const s8v*)(Kh + ((size_t)kb * 64 + lane) * 8);
        s8v kf2 = *(const s8v*)(Kh + ((size_t)(kb + 1) * 64 + lane) * 8);
        s8v vf1 = *(const s8v*)(Vh + ((size_t)kb * 64 + lane) * 8);
        s8v vf2 = *(const s8v*)(Vh + ((size_t)(kb + 1) * 64 + lane) * 8);
        s8v ka1 = {kf1[0], kf1[1], kf1[2], kf1[3], 0, 0, 0, 0};
        s8v ka2 = {kf1[4], kf1[5], kf1[6], kf1[7], 0, 0, 0, 0};
        s8v ka3 = {kf2[0], kf2[1], kf2[2], kf2[3], 0, 0, 0, 0};
        s8v ka4 = {kf2[4], kf2[5], kf2[6], kf2[7], 0, 0, 0, 0};
        f4v z = {0.f, 0.f, 0.f, 0.f};
        f4v c1 = __builtin_amdgcn_mfma_f32_16x16x32_bf16(ka1, qf, z, 0, 0, 0);
        f4v c2 = __builtin_amdgcn_mfma_f32_16x16x32_bf16(ka2, qf, z, 0, 0, 0);
        f4v c3 = __builtin_amdgcn_mfma_f32_16x16x32_bf16(ka3, qf, z, 0, 0, 0);
        f4v c4 = __builtin_amdgcn_mfma_f32_16x16x32_bf16(ka4, qf, z, 0, 0, 0);
        float p0 = __builtin_amdgcn_exp2f(c1[0]), p1 = __builtin_amdgcn_exp2f(c1[1]);
        float p2 = __builtin_amdgcn_exp2f(c1[2]), p3 = __builtin_amdgcn_exp2f(c1[3]);
        float p4 = __builtin_amdgcn_exp2f(c2[0]), p5 = __builtin_amdgcn_exp2f(c2[1]);
        float p6 = __builtin_amdgcn_exp2f(c2[2]), p7 = __builtin_amdgcn_exp2f(c2[3]);
        float p8 = __builtin_amdgcn_exp2f(c3[0]), p9 = __builtin_amdgcn_exp2f(c3[1]);
        float pa = __builtin_amdgcn_exp2f(c3[2]), pb = __builtin_amdgcn_exp2f(c3[3]);
        float pc = __builtin_amdgcn_exp2f(c4[0]), pd = __builtin_amdgcn_exp2f(c4[1]);
        float pe = __builtin_amdgcn_exp2f(c4[2]), pf_ = __builtin_amdgcn_exp2f(c4[3]);
        lA += ((p0 + p1) + (p2 + p3)) + ((p4 + p5) + (p6 + p7));
        lB += ((p8 + p9) + (pa + pb)) + ((pc + pd) + (pe + pf_));
        s8v pf1, pf2;
        pf1[0] = (short)(__float_as_uint(p0) >> 16); pf1[1] = (short)(__float_as_uint(p1) >> 16);
        pf1[2] = (short)(__float_as_uint(p2) >> 16); pf1[3] = (short)(__float_as_uint(p3) >> 16);
        pf1[4] = (short)(__float_as_uint(p4) >> 16); pf1[5] = (short)(__float_as_uint(p5) >> 16);
        pf1[6] = (short)(__float_as_uint(p6) >> 16); pf1[7] = (short)(__float_as_uint(p7) >> 16);
        pf2[0] = (short)(__float_as_uint(p8) >> 16); pf2[1] = (short)(__float_as_uint(p9) >> 16);
        pf2[2] = (short)(__float_as_uint(pa) >> 16); pf2[3] = (short)(__float_as_uint(pb) >> 16);
        pf2[4] = (short)(__float_as_uint(pc) >> 16); pf2[5] = (short)(__float_as_uint(pd) >> 16);
        pf2[6] = (short)(__float_as_uint(pe) >> 16); pf2[7] = (short)(__float_as_uint(pf_) >> 16);
        accA = __builtin_amdgcn_mfma_f32_16x16x32_bf16(vf1, pf1, accA, 0, 0, 0);
        accB = __builtin_amdgcn_mfma_f32_16x16x32_bf16(vf2, pf2, accB, 0, 0, 0);
    }
    f4v acc = {accA[0] + accB[0], accA[1] + accB[1], accA[2] + accB[2], accA[3] + accB[3]};
    float l = lA + lB;
    l += __shfl_xor(l, 16, 64);
    l += __shfl_xor(l, 32, 64);
    const int q = q0 + li;
    const size_t gidx = (size_t)(h * P + q) * KC + kc;
    *(f4v*)(pout + gidx * 16 + 4 * g) = acc;
    if (lane < 16) pl[gidx] = l;
}

// ---------------- fused merge + output projection + MLP heads ----------------
__global__ void heads_kernel(const float* __restrict__ pl, const float* __restrict__ pout,
                             const float* __restrict__ Wo, const float* __restrict__ bo,
                             const float* __restrict__ Wm1, const float* __restrict__ bm1,
                             const float* __restrict__ Wm2, const float* __restrict__ bm2,
                             const float* __restrict__ Wd1, const float* __restrict__ bd1,
                             const float* __restrict__ Wd2, const float* __restrict__ bd2,
                             float* __restrict__ out) {
    __shared__ float cs[4][D];
    __shared__ float x2[4][D];
    __shared__ float hid[4][D];
    const int r0 = blockIdx.x * 4;
    const int tid = threadIdx.x;
    const int row = tid >> 6, col = tid & 63;
    {
        const int h = col >> 4, hd = col & 15;
        const size_t gq = (size_t)(h * P + r0 + row);
        float L = 0.f, s = 0.f;
#pragma unroll
        for (int c = 0; c < KC; ++c) {
            L += pl[gq * KC + c];
            s += pout[(gq * KC + c) * 16 + hd];
        }
        cs[row][col] = s / L;
    }
    __syncthreads();
    float a = bo[col];
    for (int d = 0; d < D; ++d) a = fmaf(cs[row][d], Wo[d * D + col], a);
    x2[row][col] = a;
    __syncthreads();
    const int hc = col & 31;
    const float* W1 = (col < 32) ? Wm1 : Wd1;
    float hsum = (col < 32) ? bm1[hc] : bd1[hc];
    for (int d = 0; d < D; ++d) hsum = fmaf(x2[row][d], W1[d * 32 + hc], hsum);
    hsum = fmaxf(hsum, 0.0f);
    float w2 = (col < 32) ? Wm2[hc] : Wd2[hc];
    hid[row][col] = hsum * w2;
    __syncthreads();
    if (tid < 8) {
        int rr = tid >> 1, which = tid & 1;
        float s = which ? bd2[0] : bm2[0];
        for (int j2 = 0; j2 < 32; ++j2) s += hid[rr][which * 32 + j2];
        out[which * P + r0 + rr] = softplus_f(s);
    }
}

extern "C" void kernel_launch(void* const* d_in, const int* in_sizes, int n_in,
                              void* d_out, int out_size, void* d_ws, size_t ws_size,
                              hipStream_t stream) {
    const float* times = (const float*)d_in[0];
    const float* mom   = (const float*)d_in[1];
    const float* pos   = (const float*)d_in[2];
    const int*   pairs = (const int*)d_in[3];
    const float* Wenc  = (const float*)d_in[4];
    const float* benc  = (const float*)d_in[5];
    const float* pemb  = (const float*)d_in[6];
    const float* Wq = (const float*)d_in[7];   const float* bq = (const float*)d_in[8];
    const float* Wk = (const float*)d_in[9];   const float* bk = (const float*)d_in[10];
    const float* Wv = (const float*)d_in[11];  const float* bv = (const float*)d_in[12];
    const float* Wo = (const float*)d_in[13];  const float* bo = (const float*)d_in[14];
    const float* Wm1 = (const float*)d_in[15]; const float* bm1 = (const float*)d_in[16];
    const float* Wm2 = (const float*)d_in[17]; const float* bm2 = (const float*)d_in[18];
    const float* Wd1 = (const float*)d_in[19]; const float* bd1 = (const float*)d_in[20];
    const float* Wd2 = (const float*)d_in[21]; const float* bd2 = (const float*)d_in[22];

    char* wsb = (char*)d_ws;
    uint2* sfeats   = (uint2*)wsb;                             // NE*8 = 16 MB [reused as pout]
    int* hists      = (int*)(wsb + (size_t)NE * 8);            // NB*P = 8 MB
    int* totals     = hists + (size_t)NB * P;
    int* bin_start  = totals + P;
    unsigned short* Qb = (unsigned short*)(bin_start + P + 2); // 512 KB
    unsigned short* Kf = Qb + (size_t)H * P * 16;              // 512 KB
    unsigned short* Vf = Kf + (size_t)H * P * 16;              // 512 KB
    float* pl       = (float*)(Vf + (size_t)H * P * 16);       // H*P*KC
    float* pout     = (float*)wsb;                             // alias sfeats (dead after gather)
    float* out      = (float*)d_out;

    hist_pass<<<NB, PBT, 0, stream>>>(pairs, hists);
    scan_cols<<<P / SCB, 1024, 0, stream>>>(hists, totals);
    place_pass<<<NB, PBT, 0, stream>>>(pairs, times, mom, pos, hists, totals,
                                       bin_start, sfeats);
    gather_kernel<<<P / 2, 512, 0, stream>>>(sfeats, bin_start, Wenc, benc, pemb,
                                             Wq, bq, Wk, bk, Wv, bv, Qb, Kf, Vf);
    flash_kernel<<<H * (P / 64) * KC, 256, 0, stream>>>(Qb, Kf, Vf, pl, pout);
    heads_kernel<<<P / 4, 256, 0, stream>>>(pl, pout, Wo, bo, Wm1, bm1, Wm2, bm2,
                                            Wd1, bd1, Wd2, bd2, out);
}

// Round 15
// 122.892 us; speedup vs baseline: 1.0642x; 1.0047x over previous
//
#include <hip/hip_runtime.h>
#include <hip/hip_fp16.h>
#include <math.h>

#define NP 1000000
#define NE (2 * NP)
#define P 4096
#define D 64
#define H 4
#define HD 16

#define NB 512      // blocks for hist/place passes
#define PBT 1024    // threads per pass block
#define SCB 128     // bins per scan_cols block

#define KC 8        // K-splits across blocks for flash

typedef short s4v __attribute__((ext_vector_type(4)));
typedef short s8v __attribute__((ext_vector_type(8)));
typedef float f4v __attribute__((ext_vector_type(4)));

__device__ __forceinline__ float softplus_f(float x) {
    return fmaxf(x, 0.0f) + log1pf(__expf(-fabsf(x)));
}
__device__ __forceinline__ unsigned short f2bf_rne(float f) {
    unsigned int b = __float_as_uint(f);
    b += 0x7fffu + ((b >> 16) & 1u);
    return (unsigned short)(b >> 16);
}

// ---------------- pass A: per-block bin histogram ----------------
__global__ void __launch_bounds__(PBT) hist_pass(const int* __restrict__ pairs,
                                                 int* __restrict__ hists) {
    __shared__ int lh[P];
    const int tid = threadIdx.x, blk = blockIdx.x;
    for (int i = tid; i < P; i += PBT) lh[i] = 0;
    __syncthreads();
    const int lo = (int)(((long long)blk * NE) / NB);
    const int hi = (int)(((long long)(blk + 1) * NE) / NB);
    for (int i = lo + tid; i < hi; i += PBT) atomicAdd(&lh[pairs[i]], 1);
    __syncthreads();
    for (int i = tid; i < P; i += PBT) hists[(size_t)blk * P + i] = lh[i];
}

// ---------------- column prefix over blocks: chunked LDS transpose-scan ----------------
__global__ void __launch_bounds__(1024) scan_cols(int* __restrict__ hists,
                                                  int* __restrict__ totals) {
    __shared__ int buf[64][SCB];              // 32 KB
    const int bo = blockIdx.x * SCB;
    const int t = threadIdx.x;
    const int col = t & (SCB - 1);
    const int row = t >> 7;                   // 0..7
    int carry = 0;                            // valid for t < SCB
    for (int c = 0; c < NB / 64; ++c) {
#pragma unroll
        for (int r8 = 0; r8 < 64; r8 += 8)
            buf[r8 + row][col] = hists[(size_t)(c * 64 + r8 + row) * P + bo + col];
        __syncthreads();
        if (t < SCB) {
            int cr = carry;
            for (int r = 0; r < 64; ++r) { int v = buf[r][t]; buf[r][t] = cr; cr += v; }
            carry = cr;
        }
        __syncthreads();
#pragma unroll
        for (int r8 = 0; r8 < 64; r8 += 8)
            hists[(size_t)(c * 64 + r8 + row) * P + bo + col] = buf[r8 + row][col];
        __syncthreads();
    }
    if (t < SCB) totals[bo + t] = carry;
}

// ---- pass C: fused {bin scan + scatter fp16 features}; block 0 publishes bin_start ----
__global__ void __launch_bounds__(PBT) place_pass(
        const int* __restrict__ pairs, const float* __restrict__ times,
        const float* __restrict__ mom, const float* __restrict__ pos,
        const int* __restrict__ hists, const int* __restrict__ totals,
        int* __restrict__ bin_start, uint2* __restrict__ sfeats) {
    __shared__ int lc[P];
    __shared__ int loff[P];
    __shared__ int sdat[1024];
    const int tid = threadIdx.x, blk = blockIdx.x;
    int a[4]; int s = 0;
#pragma unroll
    for (int k2 = 0; k2 < 4; ++k2) { a[k2] = totals[tid * 4 + k2]; s += a[k2]; }
    sdat[tid] = s;
    __syncthreads();
    for (int off = 1; off < 1024; off <<= 1) {
        int v = (tid >= off) ? sdat[tid - off] : 0;
        __syncthreads();
        sdat[tid] += v;
        __syncthreads();
    }
    int run = sdat[tid] - s;
#pragma unroll
    for (int k2 = 0; k2 < 4; ++k2) {
        int i = tid * 4 + k2;
        loff[i] = run + hists[(size_t)blk * P + i];
        lc[i] = 0;
        if (blk == 0) bin_start[i] = run;
        run += a[k2];
    }
    if (blk == 0 && tid == 1023) bin_start[P] = run;
    __syncthreads();
    const int lo = (int)(((long long)blk * NE) / NB);
    const int hi = (int)(((long long)(blk + 1) * NE) / NB);
    int idx[4]; bool vld[4]; int bb[4]; uint2 ff[4];
#pragma unroll
    for (int j = 0; j < 4; ++j) {
        idx[j] = lo + tid + j * PBT;
        vld[j] = idx[j] < hi;
        int i2 = vld[j] ? idx[j] : lo;
        int ev = i2 >> 1;
        bb[j] = pairs[i2];
        __half2 tm = __floats2half2_rn(times[ev], mom[ev]);
        __half2 pz = __floats2half2_rn(pos[ev], 0.0f);
        ff[j].x = *(unsigned int*)&tm;
        ff[j].y = *(unsigned int*)&pz;
    }
    int rr[4];
#pragma unroll
    for (int j = 0; j < 4; ++j)
        rr[j] = vld[j] ? atomicAdd(&lc[bb[j]], 1) : 0;
#pragma unroll
    for (int j = 0; j < 4; ++j)
        if (vld[j]) sfeats[(size_t)loff[bb[j]] + rr[j]] = ff[j];
}

// ---------------- gather-reduce (4 waves/bin, pairwise-rcp) + fused QKV ----------------
#define PDIM(w0_, w1_, w2_, b_, j)                                             \
    {                                                                          \
        float uA = fmaf(fAx, w0_, fmaf(fAy, w1_, fmaf(fAz, w2_, b_)));         \
        float uB = fmaf(fBx, w0_, fmaf(fBy, w1_, fmaf(fBz, w2_, b_)));         \
        float pA = __builtin_amdgcn_exp2f(uA) + 1.0f;                          \
        float pB = __builtin_amdgcn_exp2f(uB) + 1.0f;                          \
        racc[j] = fmaf(pA + pB, __builtin_amdgcn_rcpf(pA * pB), racc[j]);      \
    }
#define GBODY2()                                                               \
    PDIM(w0a[0], w1a[0], w2a[0], ba[0], 0)                                     \
    PDIM(w0a[1], w1a[1], w2a[1], ba[1], 1)                                     \
    PDIM(w0a[2], w1a[2], w2a[2], ba[2], 2)                                     \
    PDIM(w0a[3], w1a[3], w2a[3], ba[3], 3)                                     \
    PDIM(w0b[0], w1b[0], w2b[0], bbv[0], 4)                                    \
    PDIM(w0b[1], w1b[1], w2b[1], bbv[1], 5)                                    \
    PDIM(w0b[2], w1b[2], w2b[2], bbv[2], 6)                                    \
    PDIM(w0b[3], w1b[3], w2b[3], bbv[3], 7)

#define SDIM(w0_, w1_, w2_, b_, j)                                             \
    {                                                                          \
        float u = fmaf(fAx, w0_, fmaf(fAy, w1_, fmaf(fAz, w2_, b_)));          \
        racc[j] += __builtin_amdgcn_rcpf(__builtin_amdgcn_exp2f(u) + 1.0f);    \
    }
#define GBODY1()                                                               \
    SDIM(w0a[0], w1a[0], w2a[0], ba[0], 0)                                     \
    SDIM(w0a[1], w1a[1], w2a[1], ba[1], 1)                                     \
    SDIM(w0a[2], w1a[2], w2a[2], ba[2], 2)                                     \
    SDIM(w0a[3], w1a[3], w2a[3], ba[3], 3)                                     \
    SDIM(w0b[0], w1b[0], w2b[0], bbv[0], 4)                                    \
    SDIM(w0b[1], w1b[1], w2b[1], bbv[1], 5)                                    \
    SDIM(w0b[2], w1b[2], w2b[2], bbv[2], 6)                                    \
    SDIM(w0b[3], w1b[3], w2b[3], bbv[3], 7)

__global__ void __launch_bounds__(512) gather_kernel(
        const uint2* __restrict__ sfeats, const int* __restrict__ bin_start,
        const float* __restrict__ Wenc, const float* __restrict__ benc,
        const float* __restrict__ pemb,
        const float* __restrict__ Wq, const float* __restrict__ bq,
        const float* __restrict__ Wk, const float* __restrict__ bk,
        const float* __restrict__ Wv, const float* __restrict__ bv,
        unsigned short* __restrict__ Qb, unsigned short* __restrict__ Kf,
        unsigned short* __restrict__ Vf) {
    __shared__ float sred[2][32][68];   // [bin-in-block][slot(4 quarters x 8 es)][dim+pad]
    __shared__ float xr[2][64];
    const int tid = threadIdx.x;
    const int wv = tid >> 6, ln = tid & 63;
    const int bi = wv >> 2, qh = wv & 3;          // bin-in-block, quarter index
    const int es = ln & 7, dg = ln >> 3;
    const int b = blockIdx.x * 2 + bi;
    const int d0 = dg * 8;
    const float C = 2.8853900817779268f;    // 2*log2(e)
    f4v w0a = *(const f4v*)(Wenc + d0);          f4v w0b = *(const f4v*)(Wenc + d0 + 4);
    f4v w1a = *(const f4v*)(Wenc + D + d0);      f4v w1b = *(const f4v*)(Wenc + D + d0 + 4);
    f4v w2a = *(const f4v*)(Wenc + 2 * D + d0);  f4v w2b = *(const f4v*)(Wenc + 2 * D + d0 + 4);
    f4v ba  = *(const f4v*)(benc + d0);          f4v bbv = *(const f4v*)(benc + d0 + 4);
    w0a *= C; w0b *= C; w1a *= C; w1b *= C; w2a *= C; w2b *= C; ba *= C; bbv *= C;
    // Pin weights in VGPRs: opaque tie prevents the compiler from rematerializing
    // the loads + *C multiplies inside the loop (R14: VGPR_Count=36 proved they
    // were NOT register-resident; VALU issue was ~3x the hand count).
    asm volatile("" : "+v"(w0a), "+v"(w0b), "+v"(w1a), "+v"(w1b),
                      "+v"(w2a), "+v"(w2b), "+v"(ba), "+v"(bbv));

    const int s0 = bin_start[b], s1 = bin_start[b + 1];
    const int cnt = s1 - s0;
    const int qs = (cnt + 3) >> 2;
    const int lo = s0 + qh * qs;
    const int hi = min(s0 + (qh + 1) * qs, s1);

    float racc[8];
#pragma unroll
    for (int j = 0; j < 8; ++j) racc[j] = 0.0f;
    int ncnt = 0;
    int base = lo;
    for (; base + 16 <= hi; base += 16) {
        uint2 uA = sfeats[base + es];
        uint2 uB = sfeats[base + 8 + es];
        float2 tA = __half22float2(*(__half2*)&uA.x);
        float fAx = tA.x, fAy = tA.y, fAz = __half2float(*(__half*)&uA.y);
        float2 tB = __half22float2(*(__half2*)&uB.x);
        float fBx = tB.x, fBy = tB.y, fBz = __half2float(*(__half*)&uB.y);
        GBODY2();
        ncnt += 2;
    }
    if (base + 8 <= hi) {
        uint2 uA = sfeats[base + es];
        float2 tA = __half22float2(*(__half2*)&uA.x);
        float fAx = tA.x, fAy = tA.y, fAz = __half2float(*(__half*)&uA.y);
        GBODY1();
        ncnt += 1;
        base += 8;
    }
    if (base < hi) {
        const int n = hi - base;
        const bool valid = es < n;
        uint2 uA = valid ? sfeats[base + es] : make_uint2(0u, 0u);
        float2 tA = __half22float2(*(__half2*)&uA.x);
        float fAx = tA.x, fAy = tA.y, fAz = __half2float(*(__half*)&uA.y);
        float save[8];
#pragma unroll
        for (int j = 0; j < 8; ++j) save[j] = racc[j];
        GBODY1();
        if (!valid) {
#pragma unroll
            for (int j = 0; j < 8; ++j) racc[j] = save[j];
        } else {
            ncnt += 1;
        }
    }
    const float fn = (float)ncnt;
    float* sw = &sred[bi][qh * 8 + es][d0];
#pragma unroll
    for (int j = 0; j < 8; ++j) sw[j] = fmaf(-2.0f, racc[j], fn);
    __syncthreads();
    if (tid < 128) {
        int bin = tid >> 6, dim = tid & 63;
        float s = 0.0f;
#pragma unroll
        for (int e2 = 0; e2 < 32; ++e2) s += sred[bin][e2][dim];
        int gb = blockIdx.x * 2 + bin;
        float c2 = (float)(bin_start[gb + 1] - bin_start[gb]);
        xr[bin][dim] = pemb[gb * D + dim] + s / fmaxf(c2, 1.0f);
    }
    __syncthreads();
    // fused QKV: 2 rows x 192 outputs; each 64-thread wave group is uniform in `which`
    if (tid < 384) {
        const int row = (tid >= 192) ? 1 : 0;
        const int o = tid - row * 192;
        const int which = o >> 6, col = o & 63;
        const float* W = (which == 0) ? Wq : ((which == 1) ? Wk : Wv);
        const float* bia = (which == 0) ? bq : ((which == 1) ? bk : bv);
        float a = bia[col];
#pragma unroll
        for (int d = 0; d < D; ++d) a = fmaf(xr[row][d], W[d * D + col], a);
        const int gr = blockIdx.x * 2 + row;
        const int h = col >> 4, hd = col & 15;
        if (which == 0) {
            Qb[((h * P + gr) << 4) + hd] = f2bf_rne(a * 0.3606737602222409f);  // 0.25*log2(e)
        } else {
            const int kb = gr >> 5, kk = gr & 31, up = kk >> 4;
            if (which == 1)
                Kf[(((size_t)h * 128 + kb) * 64 + (hd >> 2) * 16 + (kk & 15)) * 8 +
                   up * 4 + (hd & 3)] = f2bf_rne(a);
            else
                Vf[(((size_t)h * 128 + kb) * 64 + ((kk & 15) >> 2) * 16 + hd) * 8 +
                   up * 4 + (kk & 3)] = f2bf_rne(a);
        }
    }
}

// ---------------- MFMA flash attention: fragment-linear operands, dual acc ----------------
__global__ void __launch_bounds__(256) flash_kernel(
        const unsigned short* __restrict__ Qb, const unsigned short* __restrict__ Kf,
        const unsigned short* __restrict__ Vf,
        float* __restrict__ pl, float* __restrict__ pout) {
    const int bid = blockIdx.x;
    const int h  = bid & 3;
    const int qt = (bid >> 2) & 63;
    const int kc = bid >> 8;
    const int tid = threadIdx.x;
    const int wv = tid >> 6, lane = tid & 63;
    const int g = lane >> 4, li = lane & 15;
    const int q0 = qt * 64 + wv * 16;

    s8v qf = {0, 0, 0, 0, 0, 0, 0, 0};
    {
        s4v ql = *(const s4v*)(Qb + ((size_t)(h * P + q0 + li) << 4) + 4 * g);
        qf[0] = ql[0]; qf[1] = ql[1]; qf[2] = ql[2]; qf[3] = ql[3];
    }
    const unsigned short* Kh = Kf + (size_t)h * 128 * 512;
    const unsigned short* Vh = Vf + (size_t)h * 128 * 512;

    f4v accA = {0.f, 0.f, 0.f, 0.f};
    f4v accB = {0.f, 0.f, 0.f, 0.f};
    float lA = 0.f, lB = 0.f;
    const int kb0 = kc * (P / KC / 32);
    const int kb1 = kb0 + P / KC / 32;
#pragma unroll 4
    for (int kb = kb0; kb < kb1; kb += 2) {
        s8v kf1 = *(const s8v*)(Kh + ((size_t)kb * 64 + lane) * 8);
        s8v kf2 = *(const s8v*)(Kh + ((size_t)(kb + 1) * 64 + lane) * 8);
        s8v vf1 = *(const s8v*)(Vh + ((size_t)kb * 64 + lane) * 8);
        s8v vf2 = *(const s8v*)(Vh + ((size_t)(kb + 1) * 64 + lane) * 8);
        s8v ka1 = {kf1[0], kf1[1], kf1[2], kf1[3], 0, 0, 0, 0};
        s8v ka2 = {kf1[4], kf1[5], kf1[6], kf1[7], 0, 0, 0, 0};
        s8v ka3 = {kf2[0], kf2[1], kf2[2], kf2[3], 0, 0, 0, 0};
        s8v ka4 = {kf2[4], kf2[5], kf2[6], kf2[7], 0, 0, 0, 0};
        f4v z = {0.f, 0.f, 0.f, 0.f};
        f4v c1 = __builtin_amdgcn_mfma_f32_16x16x32_bf16(ka1, qf, z, 0, 0, 0);
        f4v c2 = __builtin_amdgcn_mfma_f32_16x16x32_bf16(ka2, qf, z, 0, 0, 0);
        f4v c3 = __builtin_amdgcn_mfma_f32_16x16x32_bf16(ka3, qf, z, 0, 0, 0);
        f4v c4 = __builtin_amdgcn_mfma_f32_16x16x32_bf16(ka4, qf, z, 0, 0, 0);
        float p0 = __builtin_amdgcn_exp2f(c1[0]), p1 = __builtin_amdgcn_exp2f(c1[1]);
        float p2 = __builtin_amdgcn_exp2f(c1[2]), p3 = __builtin_amdgcn_exp2f(c1[3]);
        float p4 = __builtin_amdgcn_exp2f(c2[0]), p5 = __builtin_amdgcn_exp2f(c2[1]);
        float p6 = __builtin_amdgcn_exp2f(c2[2]), p7 = __builtin_amdgcn_exp2f(c2[3]);
        float p8 = __builtin_amdgcn_exp2f(c3[0]), p9 = __builtin_amdgcn_exp2f(c3[1]);
        float pa = __builtin_amdgcn_exp2f(c3[2]), pb = __builtin_amdgcn_exp2f(c3[3]);
        float pc = __builtin_amdgcn_exp2f(c4[0]), pd = __builtin_amdgcn_exp2f(c4[1]);
        float pe = __builtin_amdgcn_exp2f(c4[2]), pf_ = __builtin_amdgcn_exp2f(c4[3]);
        lA += ((p0 + p1) + (p2 + p3)) + ((p4 + p5) + (p6 + p7));
        lB += ((p8 + p9) + (pa + pb)) + ((pc + pd) + (pe + pf_));
        s8v pf1, pf2;
        pf1[0] = (short)(__float_as_uint(p0) >> 16); pf1[1] = (short)(__float_as_uint(p1) >> 16);
        pf1[2] = (short)(__float_as_uint(p2) >> 16); pf1[3] = (short)(__float_as_uint(p3) >> 16);
        pf1[4] = (short)(__float_as_uint(p4) >> 16); pf1[5] = (short)(__float_as_uint(p5) >> 16);
        pf1[6] = (short)(__float_as_uint(p6) >> 16); pf1[7] = (short)(__float_as_uint(p7) >> 16);
        pf2[0] = (short)(__float_as_uint(p8) >> 16); pf2[1] = (short)(__float_as_uint(p9) >> 16);
        pf2[2] = (short)(__float_as_uint(pa) >> 16); pf2[3] = (short)(__float_as_uint(pb) >> 16);
        pf2[4] = (short)(__float_as_uint(pc) >> 16); pf2[5] = (short)(__float_as_uint(pd) >> 16);
        pf2[6] = (short)(__float_as_uint(pe) >> 16); pf2[7] = (short)(__float_as_uint(pf_) >> 16);
        accA = __builtin_amdgcn_mfma_f32_16x16x32_bf16(vf1, pf1, accA, 0, 0, 0);
        accB = __builtin_amdgcn_mfma_f32_16x16x32_bf16(vf2, pf2, accB, 0, 0, 0);
    }
    f4v acc = {accA[0] + accB[0], accA[1] + accB[1], accA[2] + accB[2], accA[3] + accB[3]};
    float l = lA + lB;
    l += __shfl_xor(l, 16, 64);
    l += __shfl_xor(l, 32, 64);
    const int q = q0 + li;
    const size_t gidx = (size_t)(h * P + q) * KC + kc;
    *(f4v*)(pout + gidx * 16 + 4 * g) = acc;
    if (lane < 16) pl[gidx] = l;
}

// ---------------- fused merge + output projection + MLP heads ----------------
__global__ void heads_kernel(const float* __restrict__ pl, const float* __restrict__ pout,
                             const float* __restrict__ Wo, const float* __restrict__ bo,
                             const float* __restrict__ Wm1, const float* __restrict__ bm1,
                             const float* __restrict__ Wm2, const float* __restrict__ bm2,
                             const float* __restrict__ Wd1, const float* __restrict__ bd1,
                             const float* __restrict__ Wd2, const float* __restrict__ bd2,
                             float* __restrict__ out) {
    __shared__ float cs[4][D];
    __shared__ float x2[4][D];
    __shared__ float hid[4][D];
    const int r0 = blockIdx.x * 4;
    const int tid = threadIdx.x;
    const int row = tid >> 6, col = tid & 63;
    {
        const int h = col >> 4, hd = col & 15;
        const size_t gq = (size_t)(h * P + r0 + row);
        float L = 0.f, s = 0.f;
#pragma unroll
        for (int c = 0; c < KC; ++c) {
            L += pl[gq * KC + c];
            s += pout[(gq * KC + c) * 16 + hd];
        }
        cs[row][col] = s / L;
    }
    __syncthreads();
    float a = bo[col];
    for (int d = 0; d < D; ++d) a = fmaf(cs[row][d], Wo[d * D + col], a);
    x2[row][col] = a;
    __syncthreads();
    const int hc = col & 31;
    const float* W1 = (col < 32) ? Wm1 : Wd1;
    float hsum = (col < 32) ? bm1[hc] : bd1[hc];
    for (int d = 0; d < D; ++d) hsum = fmaf(x2[row][d], W1[d * 32 + hc], hsum);
    hsum = fmaxf(hsum, 0.0f);
    float w2 = (col < 32) ? Wm2[hc] : Wd2[hc];
    hid[row][col] = hsum * w2;
    __syncthreads();
    if (tid < 8) {
        int rr = tid >> 1, which = tid & 1;
        float s = which ? bd2[0] : bm2[0];
        for (int j2 = 0; j2 < 32; ++j2) s += hid[rr][which * 32 + j2];
        out[which * P + r0 + rr] = softplus_f(s);
    }
}

extern "C" void kernel_launch(void* const* d_in, const int* in_sizes, int n_in,
                              void* d_out, int out_size, void* d_ws, size_t ws_size,
                              hipStream_t stream) {
    const float* times = (const float*)d_in[0];
    const float* mom   = (const float*)d_in[1];
    const float* pos   = (const float*)d_in[2];
    const int*   pairs = (const int*)d_in[3];
    const float* Wenc  = (const float*)d_in[4];
    const float* benc  = (const float*)d_in[5];
    const float* pemb  = (const float*)d_in[6];
    const float* Wq = (const float*)d_in[7];   const float* bq = (const float*)d_in[8];
    const float* Wk = (const float*)d_in[9];   const float* bk = (const float*)d_in[10];
    const float* Wv = (const float*)d_in[11];  const float* bv = (const float*)d_in[12];
    const float* Wo = (const float*)d_in[13];  const float* bo = (const float*)d_in[14];
    const float* Wm1 = (const float*)d_in[15]; const float* bm1 = (const float*)d_in[16];
    const float* Wm2 = (const float*)d_in[17]; const float* bm2 = (const float*)d_in[18];
    const float* Wd1 = (const float*)d_in[19]; const float* bd1 = (const float*)d_in[20];
    const float* Wd2 = (const float*)d_in[21]; const float* bd2 = (const float*)d_in[22];

    char* wsb = (char*)d_ws;
    uint2* sfeats   = (uint2*)wsb;                             // NE*8 = 16 MB [reused as pout]
    int* hists      = (int*)(wsb + (size_t)NE * 8);            // NB*P = 8 MB
    int* totals     = hists + (size_t)NB * P;
    int* bin_start  = totals + P;
    unsigned short* Qb = (unsigned short*)(bin_start + P + 2); // 512 KB
    unsigned short* Kf = Qb + (size_t)H * P * 16;              // 512 KB
    unsigned short* Vf = Kf + (size_t)H * P * 16;              // 512 KB
    float* pl       = (float*)(Vf + (size_t)H * P * 16);       // H*P*KC
    float* pout     = (float*)wsb;                             // alias sfeats (dead after gather)
    float* out      = (float*)d_out;

    hist_pass<<<NB, PBT, 0, stream>>>(pairs, hists);
    scan_cols<<<P / SCB, 1024, 0, stream>>>(hists, totals);
    place_pass<<<NB, PBT, 0, stream>>>(pairs, times, mom, pos, hists, totals,
                                       bin_start, sfeats);
    gather_kernel<<<P / 2, 512, 0, stream>>>(sfeats, bin_start, Wenc, benc, pemb,
                                             Wq, bq, Wk, bk, Wv, bv, Qb, Kf, Vf);
    flash_kernel<<<H * (P / 64) * KC, 256, 0, stream>>>(Qb, Kf, Vf, pl, pout);
    heads_kernel<<<P / 4, 256, 0, stream>>>(pl, pout, Wo, bo, Wm1, bm1, Wm2, bm2,
                                            Wd1, bd1, Wd2, bd2, out);
}

// Round 16
// 122.762 us; speedup vs baseline: 1.0654x; 1.0011x over previous
//
#include <hip/hip_runtime.h>
#include <hip/hip_fp16.h>
#include <math.h>

#define NP 1000000
#define NE (2 * NP)
#define P 4096
#define D 64
#define H 4
#define HD 16

#define NB 512      // blocks for hist/place passes
#define PBT 1024    // threads per pass block
#define SCB 128     // bins per scan_cols block

#define KC 8        // K-splits across blocks for flash

typedef short s4v __attribute__((ext_vector_type(4)));
typedef short s8v __attribute__((ext_vector_type(8)));
typedef float f4v __attribute__((ext_vector_type(4)));

__device__ __forceinline__ float softplus_f(float x) {
    return fmaxf(x, 0.0f) + log1pf(__expf(-fabsf(x)));
}
__device__ __forceinline__ unsigned short f2bf_rne(float f) {
    unsigned int b = __float_as_uint(f);
    b += 0x7fffu + ((b >> 16) & 1u);
    return (unsigned short)(b >> 16);
}

// ---------------- pass A: per-block bin histogram ----------------
__global__ void __launch_bounds__(PBT) hist_pass(const int* __restrict__ pairs,
                                                 int* __restrict__ hists) {
    __shared__ int lh[P];
    const int tid = threadIdx.x, blk = blockIdx.x;
    for (int i = tid; i < P; i += PBT) lh[i] = 0;
    __syncthreads();
    const int lo = (int)(((long long)blk * NE) / NB);
    const int hi = (int)(((long long)(blk + 1) * NE) / NB);
    for (int i = lo + tid; i < hi; i += PBT) atomicAdd(&lh[pairs[i]], 1);
    __syncthreads();
    for (int i = tid; i < P; i += PBT) hists[(size_t)blk * P + i] = lh[i];
}

// ---------------- column prefix over blocks: chunked LDS transpose-scan ----------------
__global__ void __launch_bounds__(1024) scan_cols(int* __restrict__ hists,
                                                  int* __restrict__ totals) {
    __shared__ int buf[64][SCB];              // 32 KB
    const int bo = blockIdx.x * SCB;
    const int t = threadIdx.x;
    const int col = t & (SCB - 1);
    const int row = t >> 7;                   // 0..7
    int carry = 0;                            // valid for t < SCB
    for (int c = 0; c < NB / 64; ++c) {
#pragma unroll
        for (int r8 = 0; r8 < 64; r8 += 8)
            buf[r8 + row][col] = hists[(size_t)(c * 64 + r8 + row) * P + bo + col];
        __syncthreads();
        if (t < SCB) {
            int cr = carry;
            for (int r = 0; r < 64; ++r) { int v = buf[r][t]; buf[r][t] = cr; cr += v; }
            carry = cr;
        }
        __syncthreads();
#pragma unroll
        for (int r8 = 0; r8 < 64; r8 += 8)
            hists[(size_t)(c * 64 + r8 + row) * P + bo + col] = buf[r8 + row][col];
        __syncthreads();
    }
    if (t < SCB) totals[bo + t] = carry;
}

// ---- pass C: fused {bin scan + scatter fp16 features}; block 0 publishes bin_start ----
__global__ void __launch_bounds__(PBT) place_pass(
        const int* __restrict__ pairs, const float* __restrict__ times,
        const float* __restrict__ mom, const float* __restrict__ pos,
        const int* __restrict__ hists, const int* __restrict__ totals,
        int* __restrict__ bin_start, uint2* __restrict__ sfeats) {
    __shared__ int lc[P];
    __shared__ int loff[P];
    __shared__ int sdat[1024];
    const int tid = threadIdx.x, blk = blockIdx.x;
    int a[4]; int s = 0;
#pragma unroll
    for (int k2 = 0; k2 < 4; ++k2) { a[k2] = totals[tid * 4 + k2]; s += a[k2]; }
    sdat[tid] = s;
    __syncthreads();
    for (int off = 1; off < 1024; off <<= 1) {
        int v = (tid >= off) ? sdat[tid - off] : 0;
        __syncthreads();
        sdat[tid] += v;
        __syncthreads();
    }
    int run = sdat[tid] - s;
#pragma unroll
    for (int k2 = 0; k2 < 4; ++k2) {
        int i = tid * 4 + k2;
        loff[i] = run + hists[(size_t)blk * P + i];
        lc[i] = 0;
        if (blk == 0) bin_start[i] = run;
        run += a[k2];
    }
    if (blk == 0 && tid == 1023) bin_start[P] = run;
    __syncthreads();
    const int lo = (int)(((long long)blk * NE) / NB);
    const int hi = (int)(((long long)(blk + 1) * NE) / NB);
    int idx[4]; bool vld[4]; int bb[4]; uint2 ff[4];
#pragma unroll
    for (int j = 0; j < 4; ++j) {
        idx[j] = lo + tid + j * PBT;
        vld[j] = idx[j] < hi;
        int i2 = vld[j] ? idx[j] : lo;
        int ev = i2 >> 1;
        bb[j] = pairs[i2];
        __half2 tm = __floats2half2_rn(times[ev], mom[ev]);
        __half2 pz = __floats2half2_rn(pos[ev], 0.0f);
        ff[j].x = *(unsigned int*)&tm;
        ff[j].y = *(unsigned int*)&pz;
    }
    int rr[4];
#pragma unroll
    for (int j = 0; j < 4; ++j)
        rr[j] = vld[j] ? atomicAdd(&lc[bb[j]], 1) : 0;
#pragma unroll
    for (int j = 0; j < 4; ++j)
        if (vld[j]) sfeats[(size_t)loff[bb[j]] + rr[j]] = ff[j];
}

// ---------------- gather-reduce (4 waves/bin, pairwise-rcp) + fused QKV ----------------
#define PDIM(w0_, w1_, w2_, b_, j)                                             \
    {                                                                          \
        float uA = fmaf(fAx, w0_, fmaf(fAy, w1_, fmaf(fAz, w2_, b_)));         \
        float uB = fmaf(fBx, w0_, fmaf(fBy, w1_, fmaf(fBz, w2_, b_)));         \
        float pA = __builtin_amdgcn_exp2f(uA) + 1.0f;                          \
        float pB = __builtin_amdgcn_exp2f(uB) + 1.0f;                          \
        racc[j] = fmaf(pA + pB, __builtin_amdgcn_rcpf(pA * pB), racc[j]);      \
    }
#define GBODY2()                                                               \
    PDIM(w0a[0], w1a[0], w2a[0], ba[0], 0)                                     \
    PDIM(w0a[1], w1a[1], w2a[1], ba[1], 1)                                     \
    PDIM(w0a[2], w1a[2], w2a[2], ba[2], 2)                                     \
    PDIM(w0a[3], w1a[3], w2a[3], ba[3], 3)                                     \
    PDIM(w0b[0], w1b[0], w2b[0], bbv[0], 4)                                    \
    PDIM(w0b[1], w1b[1], w2b[1], bbv[1], 5)                                    \
    PDIM(w0b[2], w1b[2], w2b[2], bbv[2], 6)                                    \
    PDIM(w0b[3], w1b[3], w2b[3], bbv[3], 7)

#define SDIM(w0_, w1_, w2_, b_, j)                                             \
    {                                                                          \
        float u = fmaf(fAx, w0_, fmaf(fAy, w1_, fmaf(fAz, w2_, b_)));          \
        racc[j] += __builtin_amdgcn_rcpf(__builtin_amdgcn_exp2f(u) + 1.0f);    \
    }
#define GBODY1()                                                               \
    SDIM(w0a[0], w1a[0], w2a[0], ba[0], 0)                                     \
    SDIM(w0a[1], w1a[1], w2a[1], ba[1], 1)                                     \
    SDIM(w0a[2], w1a[2], w2a[2], ba[2], 2)                                     \
    SDIM(w0a[3], w1a[3], w2a[3], ba[3], 3)                                     \
    SDIM(w0b[0], w1b[0], w2b[0], bbv[0], 4)                                    \
    SDIM(w0b[1], w1b[1], w2b[1], bbv[1], 5)                                    \
    SDIM(w0b[2], w1b[2], w2b[2], bbv[2], 6)                                    \
    SDIM(w0b[3], w1b[3], w2b[3], bbv[3], 7)

// __launch_bounds__(512, 2): allow the allocator a large VGPR budget.
// R15 evidence: with default budget the kernel compiled to 32 VGPRs -- too few
// to hold the 32 pinned weight regs + racc[8], so the allocator spilled/
// rematerialized weights in the hot loop (the 3x VALU-issue inflation).
__global__ void __launch_bounds__(512, 2) gather_kernel(
        const uint2* __restrict__ sfeats, const int* __restrict__ bin_start,
        const float* __restrict__ Wenc, const float* __restrict__ benc,
        const float* __restrict__ pemb,
        const float* __restrict__ Wq, const float* __restrict__ bq,
        const float* __restrict__ Wk, const float* __restrict__ bk,
        const float* __restrict__ Wv, const float* __restrict__ bv,
        unsigned short* __restrict__ Qb, unsigned short* __restrict__ Kf,
        unsigned short* __restrict__ Vf) {
    __shared__ float sred[2][32][68];   // [bin-in-block][slot(4 quarters x 8 es)][dim+pad]
    __shared__ float xr[2][64];
    const int tid = threadIdx.x;
    const int wv = tid >> 6, ln = tid & 63;
    const int bi = wv >> 2, qh = wv & 3;          // bin-in-block, quarter index
    const int es = ln & 7, dg = ln >> 3;
    const int b = blockIdx.x * 2 + bi;
    const int d0 = dg * 8;
    const float C = 2.8853900817779268f;    // 2*log2(e)
    f4v w0a = *(const f4v*)(Wenc + d0);          f4v w0b = *(const f4v*)(Wenc + d0 + 4);
    f4v w1a = *(const f4v*)(Wenc + D + d0);      f4v w1b = *(const f4v*)(Wenc + D + d0 + 4);
    f4v w2a = *(const f4v*)(Wenc + 2 * D + d0);  f4v w2b = *(const f4v*)(Wenc + 2 * D + d0 + 4);
    f4v ba  = *(const f4v*)(benc + d0);          f4v bbv = *(const f4v*)(benc + d0 + 4);
    w0a *= C; w0b *= C; w1a *= C; w1b *= C; w2a *= C; w2b *= C; ba *= C; bbv *= C;
    // Pin weights in VGPRs (see R14/R15 notes).
    asm volatile("" : "+v"(w0a), "+v"(w0b), "+v"(w1a), "+v"(w1b),
                      "+v"(w2a), "+v"(w2b), "+v"(ba), "+v"(bbv));

    const int s0 = bin_start[b], s1 = bin_start[b + 1];
    const int cnt = s1 - s0;
    const int qs = (cnt + 3) >> 2;
    const int lo = s0 + qh * qs;
    const int hi = min(s0 + (qh + 1) * qs, s1);

    float racc[8];
#pragma unroll
    for (int j = 0; j < 8; ++j) racc[j] = 0.0f;
    int ncnt = 0;
    int base = lo;
    for (; base + 16 <= hi; base += 16) {
        uint2 uA = sfeats[base + es];
        uint2 uB = sfeats[base + 8 + es];
        float2 tA = __half22float2(*(__half2*)&uA.x);
        float fAx = tA.x, fAy = tA.y, fAz = __half2float(*(__half*)&uA.y);
        float2 tB = __half22float2(*(__half2*)&uB.x);
        float fBx = tB.x, fBy = tB.y, fBz = __half2float(*(__half*)&uB.y);
        GBODY2();
        ncnt += 2;
    }
    if (base + 8 <= hi) {
        uint2 uA = sfeats[base + es];
        float2 tA = __half22float2(*(__half2*)&uA.x);
        float fAx = tA.x, fAy = tA.y, fAz = __half2float(*(__half*)&uA.y);
        GBODY1();
        ncnt += 1;
        base += 8;
    }
    if (base < hi) {
        const int n = hi - base;
        const bool valid = es < n;
        uint2 uA = valid ? sfeats[base + es] : make_uint2(0u, 0u);
        float2 tA = __half22float2(*(__half2*)&uA.x);
        float fAx = tA.x, fAy = tA.y, fAz = __half2float(*(__half*)&uA.y);
        float save[8];
#pragma unroll
        for (int j = 0; j < 8; ++j) save[j] = racc[j];
        GBODY1();
        if (!valid) {
#pragma unroll
            for (int j = 0; j < 8; ++j) racc[j] = save[j];
        } else {
            ncnt += 1;
        }
    }
    const float fn = (float)ncnt;
    float* sw = &sred[bi][qh * 8 + es][d0];
#pragma unroll
    for (int j = 0; j < 8; ++j) sw[j] = fmaf(-2.0f, racc[j], fn);
    __syncthreads();
    if (tid < 128) {
        int bin = tid >> 6, dim = tid & 63;
        float s = 0.0f;
#pragma unroll
        for (int e2 = 0; e2 < 32; ++e2) s += sred[bin][e2][dim];
        int gb = blockIdx.x * 2 + bin;
        float c2 = (float)(bin_start[gb + 1] - bin_start[gb]);
        xr[bin][dim] = pemb[gb * D + dim] + s / fmaxf(c2, 1.0f);
    }
    __syncthreads();
    // fused QKV: 2 rows x 192 outputs; each 64-thread wave group is uniform in `which`
    if (tid < 384) {
        const int row = (tid >= 192) ? 1 : 0;
        const int o = tid - row * 192;
        const int which = o >> 6, col = o & 63;
        const float* W = (which == 0) ? Wq : ((which == 1) ? Wk : Wv);
        const float* bia = (which == 0) ? bq : ((which == 1) ? bk : bv);
        float a = bia[col];
#pragma unroll
        for (int d = 0; d < D; ++d) a = fmaf(xr[row][d], W[d * D + col], a);
        const int gr = blockIdx.x * 2 + row;
        const int h = col >> 4, hd = col & 15;
        if (which == 0) {
            Qb[((h * P + gr) << 4) + hd] = f2bf_rne(a * 0.3606737602222409f);  // 0.25*log2(e)
        } else {
            const int kb = gr >> 5, kk = gr & 31, up = kk >> 4;
            if (which == 1)
                Kf[(((size_t)h * 128 + kb) * 64 + (hd >> 2) * 16 + (kk & 15)) * 8 +
                   up * 4 + (hd & 3)] = f2bf_rne(a);
            else
                Vf[(((size_t)h * 128 + kb) * 64 + ((kk & 15) >> 2) * 16 + hd) * 8 +
                   up * 4 + (kk & 3)] = f2bf_rne(a);
        }
    }
}

// ---------------- MFMA flash attention: fragment-linear operands, dual acc ----------------
__global__ void __launch_bounds__(256) flash_kernel(
        const unsigned short* __restrict__ Qb, const unsigned short* __restrict__ Kf,
        const unsigned short* __restrict__ Vf,
        float* __restrict__ pl, float* __restrict__ pout) {
    const int bid = blockIdx.x;
    const int h  = bid & 3;
    const int qt = (bid >> 2) & 63;
    const int kc = bid >> 8;
    const int tid = threadIdx.x;
    const int wv = tid >> 6, lane = tid & 63;
    const int g = lane >> 4, li = lane & 15;
    const int q0 = qt * 64 + wv * 16;

    s8v qf = {0, 0, 0, 0, 0, 0, 0, 0};
    {
        s4v ql = *(const s4v*)(Qb + ((size_t)(h * P + q0 + li) << 4) + 4 * g);
        qf[0] = ql[0]; qf[1] = ql[1]; qf[2] = ql[2]; qf[3] = ql[3];
    }
    const unsigned short* Kh = Kf + (size_t)h * 128 * 512;
    const unsigned short* Vh = Vf + (size_t)h * 128 * 512;

    f4v accA = {0.f, 0.f, 0.f, 0.f};
    f4v accB = {0.f, 0.f, 0.f, 0.f};
    float lA = 0.f, lB = 0.f;
    const int kb0 = kc * (P / KC / 32);
    const int kb1 = kb0 + P / KC / 32;
#pragma unroll 4
    for (int kb = kb0; kb < kb1; kb += 2) {
        s8v kf1 = *(const s8v*)(Kh + ((size_t)kb * 64 + lane) * 8);
        s8v kf2 = *(const s8v*)(Kh + ((size_t)(kb + 1) * 64 + lane) * 8);
        s8v vf1 = *(const s8v*)(Vh + ((size_t)kb * 64 + lane) * 8);
        s8v vf2 = *(const s8v*)(Vh + ((size_t)(kb + 1) * 64 + lane) * 8);
        s8v ka1 = {kf1[0], kf1[1], kf1[2], kf1[3], 0, 0, 0, 0};
        s8v ka2 = {kf1[4], kf1[5], kf1[6], kf1[7], 0, 0, 0, 0};
        s8v ka3 = {kf2[0], kf2[1], kf2[2], kf2[3], 0, 0, 0, 0};
        s8v ka4 = {kf2[4], kf2[5], kf2[6], kf2[7], 0, 0, 0, 0};
        f4v z = {0.f, 0.f, 0.f, 0.f};
        f4v c1 = __builtin_amdgcn_mfma_f32_16x16x32_bf16(ka1, qf, z, 0, 0, 0);
        f4v c2 = __builtin_amdgcn_mfma_f32_16x16x32_bf16(ka2, qf, z, 0, 0, 0);
        f4v c3 = __builtin_amdgcn_mfma_f32_16x16x32_bf16(ka3, qf, z, 0, 0, 0);
        f4v c4 = __builtin_amdgcn_mfma_f32_16x16x32_bf16(ka4, qf, z, 0, 0, 0);
        float p0 = __builtin_amdgcn_exp2f(c1[0]), p1 = __builtin_amdgcn_exp2f(c1[1]);
        float p2 = __builtin_amdgcn_exp2f(c1[2]), p3 = __builtin_amdgcn_exp2f(c1[3]);
        float p4 = __builtin_amdgcn_exp2f(c2[0]), p5 = __builtin_amdgcn_exp2f(c2[1]);
        float p6 = __builtin_amdgcn_exp2f(c2[2]), p7 = __builtin_amdgcn_exp2f(c2[3]);
        float p8 = __builtin_amdgcn_exp2f(c3[0]), p9 = __builtin_amdgcn_exp2f(c3[1]);
        float pa = __builtin_amdgcn_exp2f(c3[2]), pb = __builtin_amdgcn_exp2f(c3[3]);
        float pc = __builtin_amdgcn_exp2f(c4[0]), pd = __builtin_amdgcn_exp2f(c4[1]);
        float pe = __builtin_amdgcn_exp2f(c4[2]), pf_ = __builtin_amdgcn_exp2f(c4[3]);
        lA += ((p0 + p1) + (p2 + p3)) + ((p4 + p5) + (p6 + p7));
        lB += ((p8 + p9) + (pa + pb)) + ((pc + pd) + (pe + pf_));
        s8v pf1, pf2;
        pf1[0] = (short)(__float_as_uint(p0) >> 16); pf1[1] = (short)(__float_as_uint(p1) >> 16);
        pf1[2] = (short)(__float_as_uint(p2) >> 16); pf1[3] = (short)(__float_as_uint(p3) >> 16);
        pf1[4] = (short)(__float_as_uint(p4) >> 16); pf1[5] = (short)(__float_as_uint(p5) >> 16);
        pf1[6] = (short)(__float_as_uint(p6) >> 16); pf1[7] = (short)(__float_as_uint(p7) >> 16);
        pf2[0] = (short)(__float_as_uint(p8) >> 16); pf2[1] = (short)(__float_as_uint(p9) >> 16);
        pf2[2] = (short)(__float_as_uint(pa) >> 16); pf2[3] = (short)(__float_as_uint(pb) >> 16);
        pf2[4] = (short)(__float_as_uint(pc) >> 16); pf2[5] = (short)(__float_as_uint(pd) >> 16);
        pf2[6] = (short)(__float_as_uint(pe) >> 16); pf2[7] = (short)(__float_as_uint(pf_) >> 16);
        accA = __builtin_amdgcn_mfma_f32_16x16x32_bf16(vf1, pf1, accA, 0, 0, 0);
        accB = __builtin_amdgcn_mfma_f32_16x16x32_bf16(vf2, pf2, accB, 0, 0, 0);
    }
    f4v acc = {accA[0] + accB[0], accA[1] + accB[1], accA[2] + accB[2], accA[3] + accB[3]};
    float l = lA + lB;
    l += __shfl_xor(l, 16, 64);
    l += __shfl_xor(l, 32, 64);
    const int q = q0 + li;
    const size_t gidx = (size_t)(h * P + q) * KC + kc;
    *(f4v*)(pout + gidx * 16 + 4 * g) = acc;
    if (lane < 16) pl[gidx] = l;
}

// ---------------- fused merge + output projection + MLP heads ----------------
__global__ void heads_kernel(const float* __restrict__ pl, const float* __restrict__ pout,
                             const float* __restrict__ Wo, const float* __restrict__ bo,
                             const float* __restrict__ Wm1, const float* __restrict__ bm1,
                             const float* __restrict__ Wm2, const float* __restrict__ bm2,
                             const float* __restrict__ Wd1, const float* __restrict__ bd1,
                             const float* __restrict__ Wd2, const float* __restrict__ bd2,
                             float* __restrict__ out) {
    __shared__ float cs[4][D];
    __shared__ float x2[4][D];
    __shared__ float hid[4][D];
    const int r0 = blockIdx.x * 4;
    const int tid = threadIdx.x;
    const int row = tid >> 6, col = tid & 63;
    {
        const int h = col >> 4, hd = col & 15;
        const size_t gq = (size_t)(h * P + r0 + row);
        float L = 0.f, s = 0.f;
#pragma unroll
        for (int c = 0; c < KC; ++c) {
            L += pl[gq * KC + c];
            s += pout[(gq * KC + c) * 16 + hd];
        }
        cs[row][col] = s / L;
    }
    __syncthreads();
    float a = bo[col];
    for (int d = 0; d < D; ++d) a = fmaf(cs[row][d], Wo[d * D + col], a);
    x2[row][col] = a;
    __syncthreads();
    const int hc = col & 31;
    const float* W1 = (col < 32) ? Wm1 : Wd1;
    float hsum = (col < 32) ? bm1[hc] : bd1[hc];
    for (int d = 0; d < D; ++d) hsum = fmaf(x2[row][d], W1[d * 32 + hc], hsum);
    hsum = fmaxf(hsum, 0.0f);
    float w2 = (col < 32) ? Wm2[hc] : Wd2[hc];
    hid[row][col] = hsum * w2;
    __syncthreads();
    if (tid < 8) {
        int rr = tid >> 1, which = tid & 1;
        float s = which ? bd2[0] : bm2[0];
        for (int j2 = 0; j2 < 32; ++j2) s += hid[rr][which * 32 + j2];
        out[which * P + r0 + rr] = softplus_f(s);
    }
}

extern "C" void kernel_launch(void* const* d_in, const int* in_sizes, int n_in,
                              void* d_out, int out_size, void* d_ws, size_t ws_size,
                              hipStream_t stream) {
    const float* times = (const float*)d_in[0];
    const float* mom   = (const float*)d_in[1];
    const float* pos   = (const float*)d_in[2];
    const int*   pairs = (const int*)d_in[3];
    const float* Wenc  = (const float*)d_in[4];
    const float* benc  = (const float*)d_in[5];
    const float* pemb  = (const float*)d_in[6];
    const float* Wq = (const float*)d_in[7];   const float* bq = (const float*)d_in[8];
    const float* Wk = (const float*)d_in[9];   const float* bk = (const float*)d_in[10];
    const float* Wv = (const float*)d_in[11];  const float* bv = (const float*)d_in[12];
    const float* Wo = (const float*)d_in[13];  const float* bo = (const float*)d_in[14];
    const float* Wm1 = (const float*)d_in[15]; const float* bm1 = (const float*)d_in[16];
    const float* Wm2 = (const float*)d_in[17]; const float* bm2 = (const float*)d_in[18];
    const float* Wd1 = (const float*)d_in[19]; const float* bd1 = (const float*)d_in[20];
    const float* Wd2 = (const float*)d_in[21]; const float* bd2 = (const float*)d_in[22];

    char* wsb = (char*)d_ws;
    uint2* sfeats   = (uint2*)wsb;                             // NE*8 = 16 MB [reused as pout]
    int* hists      = (int*)(wsb + (size_t)NE * 8);            // NB*P = 8 MB
    int* totals     = hists + (size_t)NB * P;
    int* bin_start  = totals + P;
    unsigned short* Qb = (unsigned short*)(bin_start + P + 2); // 512 KB
    unsigned short* Kf = Qb + (size_t)H * P * 16;              // 512 KB
    unsigned short* Vf = Kf + (size_t)H * P * 16;              // 512 KB
    float* pl       = (float*)(Vf + (size_t)H * P * 16);       // H*P*KC
    float* pout     = (float*)wsb;                             // alias sfeats (dead after gather)
    float* out      = (float*)d_out;

    hist_pass<<<NB, PBT, 0, stream>>>(pairs, hists);
    scan_cols<<<P / SCB, 1024, 0, stream>>>(hists, totals);
    place_pass<<<NB, PBT, 0, stream>>>(pairs, times, mom, pos, hists, totals,
                                       bin_start, sfeats);
    gather_kernel<<<P / 2, 512, 0, stream>>>(sfeats, bin_start, Wenc, benc, pemb,
                                             Wq, bq, Wk, bk, Wv, bv, Qb, Kf, Vf);
    flash_kernel<<<H * (P / 64) * KC, 256, 0, stream>>>(Qb, Kf, Vf, pl, pout);
    heads_kernel<<<P / 4, 256, 0, stream>>>(pl, pout, Wo, bo, Wm1, bm1, Wm2, bm2,
                                            Wd1, bd1, Wd2, bd2, out);
}